// Round 1
// baseline (2389.805 us; speedup 1.0000x reference)
//
#include <hip/hip_runtime.h>
#include <cmath>

// Forest constants (match reference)
#define NTREE 256
#define DEPTH_ 8
#define MPT 511                 // nodes per tree = 2^(D+1)-1
#define NNODE (NTREE * MPT)     // 130816
#define HS 128

constexpr int NT = 32;   // nodes per block
constexpr int NTH = 16;  // nodes per thread (half-block split)
constexpr int BT = 256;  // threads per block

__device__ __forceinline__ float sigf(float x) { return 1.0f / (1.0f + expf(-x)); }

// MODE: 0 = bottom-up leaf, 1 = bottom-up internal, 2 = top-down root, 3 = top-down internal
template <int MODE>
__global__ void __launch_bounds__(BT)
level_kernel(int t,
             const float* __restrict__ X,    // N x 128
             const float* __restrict__ Wp,   // 384 x KW  (iou over [x(;h_bu)])
             const float* __restrict__ Up,   // 384 x 128 (iou over h_tild/h_par), MODE 1,3
             const float* __restrict__ bp,   // 384
             const float* __restrict__ Ufp,  // 128 x 128 (forget gate), MODE 1,3
             const float* __restrict__ bfp,  // 128
             const float* __restrict__ hbu,  // N x 128 (MODE 2,3)
             float* __restrict__ hout,       // h_bu (BU) or h_td (TD)
             float* __restrict__ cws)        // c state (shared across passes)
{
  constexpr int  KW   = (MODE <= 1) ? 128 : 256;          // W row length
  constexpr bool HASU = (MODE == 1 || MODE == 3);
  constexpr bool HASF = HASU;
  constexpr int  NCH  = (MODE == 1) ? 2 : 1;              // children feeding f
  constexpr int  KA   = (MODE == 0) ? 128 : (MODE == 3 ? 384 : 256); // staged input width

  __shared__ float sA[NT][KA];                                      // [x | (h_bu) | (h_tild/h_par)]
  __shared__ float sFH[HASF ? ((MODE == 1 ? 2 : 1) * NT * HS) : 1]; // children h rows (MODE1)
  __shared__ int   sG[NT];
  __shared__ int   sC[NT];

  const int tid = threadIdx.x;
  const int ch  = tid & 127;   // hidden-unit lane; owns iou channels ch, ch+128, ch+256
  const int nh  = tid >> 7;    // node half
  const int n0  = nh * NTH;

  if (tid < NT) {
    int v = blockIdx.x * NT + tid;
    int b = v >> t;
    int j = ((1 << t) - 1) + (v & ((1 << t) - 1));
    int g = b * MPT + j;
    sG[tid] = g;
    int cc_ = 0;
    if (MODE == 1) cc_ = g + j + 1;                  // left child (right = +1)
    else if (MODE == 3) cc_ = b * MPT + ((j - 1) >> 1); // parent
    sC[tid] = cc_;
  }
  __syncthreads();

  // ---------------- stage inputs into LDS (all coalesced float4) ----------------
  for (int idx = tid; idx < NT * 32; idx += BT) {     // x rows -> sA[n][0:128]
    int n = idx >> 5, e = idx & 31;
    float4 v = reinterpret_cast<const float4*>(X)[(size_t)sG[n] * 32 + e];
    *reinterpret_cast<float4*>(&sA[n][e * 4]) = v;
  }
  if constexpr (MODE == 2 || MODE == 3) {             // h_bu rows -> sA[n][128:256]
    for (int idx = tid; idx < NT * 32; idx += BT) {
      int n = idx >> 5, e = idx & 31;
      float4 v = reinterpret_cast<const float4*>(hbu)[(size_t)sG[n] * 32 + e];
      *reinterpret_cast<float4*>(&sA[n][128 + e * 4]) = v;
    }
  }
  if constexpr (MODE == 3) {                          // h_td[parent] -> sA[n][256:384]
    for (int idx = tid; idx < NT * 32; idx += BT) {
      int n = idx >> 5, e = idx & 31;
      float4 v = reinterpret_cast<const float4*>(hout)[(size_t)sC[n] * 32 + e];
      *reinterpret_cast<float4*>(&sA[n][256 + e * 4]) = v;
    }
  }
  if constexpr (MODE == 1) {                          // both children h (contiguous 256 floats)
    for (int idx = tid; idx < NT * 64; idx += BT) {
      int n = idx >> 6, e = idx & 63;
      float4 v = reinterpret_cast<const float4*>(hout)[(size_t)sC[n] * 32 + e];
      int s = e >> 5, k4 = e & 31;
      *reinterpret_cast<float4*>(&sFH[((s * NT + n) * HS) + k4 * 4]) = v;
    }
  }
  __syncthreads();
  if constexpr (MODE == 1) {                          // h_tild = h_l + h_r -> sA[n][128:256]
    for (int idx = tid; idx < NT * HS; idx += BT) {
      int n = idx >> 7, k = idx & 127;
      sA[n][128 + k] = sFH[n * HS + k] + sFH[(NT + n) * HS + k];
    }
    __syncthreads();
  }

  // ---------------- forget-gate matvecs (f = sigmoid(Uf h + bf); fc = f*c) -------
  float fc[NCH][NTH];
  if constexpr (HASF) {
    float facc[NCH][NTH];
    const float bfv = bfp[ch];
#pragma unroll
    for (int s = 0; s < NCH; ++s)
#pragma unroll
      for (int n = 0; n < NTH; ++n) facc[s][n] = bfv;
    const float4* uf4 = reinterpret_cast<const float4*>(Ufp + (size_t)ch * HS);
#pragma unroll 2
    for (int k4 = 0; k4 < HS / 4; ++k4) {
      float4 w = uf4[k4];
#pragma unroll
      for (int s = 0; s < NCH; ++s) {
#pragma unroll
        for (int n = 0; n < NTH; ++n) {
          const float* src = (MODE == 1) ? &sFH[(s * NT + (n0 + n)) * HS + k4 * 4]
                                         : &sA[n0 + n][256 + k4 * 4];
          float4 a = *reinterpret_cast<const float4*>(src);
          facc[s][n] += w.x * a.x + w.y * a.y + w.z * a.z + w.w * a.w;
        }
      }
    }
#pragma unroll
    for (int s = 0; s < NCH; ++s)
#pragma unroll
      for (int n = 0; n < NTH; ++n) {
        float f = sigf(facc[s][n]);
        int gc = (MODE == 1) ? (sC[n0 + n] + s) : sC[n0 + n];
        fc[s][n] = f * cws[(size_t)gc * HS + ch];
      }
  }

  // ---------------- iou = W @ A[0:KW] (+ U @ A[KA-128:KA]) + b -------------------
  float acc[3][NTH];
#pragma unroll
  for (int cc = 0; cc < 3; ++cc) {
    float bv = bp[ch + cc * 128];
#pragma unroll
    for (int n = 0; n < NTH; ++n) acc[cc][n] = bv;
  }
  {
    const float4* w4_0 = reinterpret_cast<const float4*>(Wp + (size_t)(ch)       * KW);
    const float4* w4_1 = reinterpret_cast<const float4*>(Wp + (size_t)(ch + 128) * KW);
    const float4* w4_2 = reinterpret_cast<const float4*>(Wp + (size_t)(ch + 256) * KW);
#pragma unroll 2
    for (int k4 = 0; k4 < KW / 4; ++k4) {
      float4 w0 = w4_0[k4], w1 = w4_1[k4], w2 = w4_2[k4];
#pragma unroll
      for (int n = 0; n < NTH; ++n) {
        float4 a = *reinterpret_cast<const float4*>(&sA[n0 + n][k4 * 4]);
        acc[0][n] += w0.x * a.x + w0.y * a.y + w0.z * a.z + w0.w * a.w;
        acc[1][n] += w1.x * a.x + w1.y * a.y + w1.z * a.z + w1.w * a.w;
        acc[2][n] += w2.x * a.x + w2.y * a.y + w2.z * a.z + w2.w * a.w;
      }
    }
  }
  if constexpr (HASU) {
    constexpr int OFF = KA - 128;
    const float4* u4_0 = reinterpret_cast<const float4*>(Up + (size_t)(ch)       * HS);
    const float4* u4_1 = reinterpret_cast<const float4*>(Up + (size_t)(ch + 128) * HS);
    const float4* u4_2 = reinterpret_cast<const float4*>(Up + (size_t)(ch + 256) * HS);
#pragma unroll 2
    for (int k4 = 0; k4 < HS / 4; ++k4) {
      float4 w0 = u4_0[k4], w1 = u4_1[k4], w2 = u4_2[k4];
#pragma unroll
      for (int n = 0; n < NTH; ++n) {
        float4 a = *reinterpret_cast<const float4*>(&sA[n0 + n][OFF + k4 * 4]);
        acc[0][n] += w0.x * a.x + w0.y * a.y + w0.z * a.z + w0.w * a.w;
        acc[1][n] += w1.x * a.x + w1.y * a.y + w1.z * a.z + w1.w * a.w;
        acc[2][n] += w2.x * a.x + w2.y * a.y + w2.z * a.z + w2.w * a.w;
      }
    }
  }

  // ---------------- gating: thread already holds i,o,u and fc for unit `ch` -----
#pragma unroll
  for (int n = 0; n < NTH; ++n) {
    float cred = 0.0f;
    if constexpr (MODE == 1) cred = fc[0][n] + fc[1][n];
    if constexpr (MODE == 3) cred = fc[0][n];
    float cn = sigf(acc[0][n]) * tanhf(acc[2][n]) + cred;
    float hn = sigf(acc[1][n]) * tanhf(cn);
    size_t off = (size_t)sG[n0 + n] * HS + ch;
    hout[off] = hn;
    cws[off]  = cn;
  }
}

__global__ void __launch_bounds__(128)
finalize_kernel(const float* __restrict__ h_bu, const float* __restrict__ h_td,
                float* __restrict__ out)
{
  int b = blockIdx.x, ch = threadIdx.x;
  out[(size_t)b * 256 + ch] = h_bu[((size_t)b * MPT) * HS + ch];
  const float* base = h_td + ((size_t)b * MPT + 255) * HS + ch; // leaves j in [255,511)
  float s = 0.0f;
#pragma unroll 8
  for (int l = 0; l < 256; ++l) s += base[(size_t)l * HS];
  out[(size_t)b * 256 + 128 + ch] = s * (1.0f / 256.0f);
}

extern "C" void kernel_launch(void* const* d_in, const int* in_sizes, int n_in,
                              void* d_out, int out_size, void* d_ws, size_t ws_size,
                              hipStream_t stream) {
  const float* X     = (const float*)d_in[0];
  const float* W_bu  = (const float*)d_in[3];
  const float* U_bu  = (const float*)d_in[4];
  const float* b_bu  = (const float*)d_in[5];
  const float* Uf_bu = (const float*)d_in[6];
  const float* bf_bu = (const float*)d_in[7];
  const float* W_td  = (const float*)d_in[8];
  const float* U_td  = (const float*)d_in[9];
  const float* b_td  = (const float*)d_in[10];
  const float* Uf_td = (const float*)d_in[11];
  const float* bf_td = (const float*)d_in[12];

  // workspace: h_bu | c (shared bu/td) | h_td  — 3 * N * 128 f32 ≈ 201 MB
  float* h_bu = (float*)d_ws;
  float* c_st = h_bu + (size_t)NNODE * HS;
  float* h_td = c_st + (size_t)NNODE * HS;

  dim3 blk(BT);

  // ---- bottom-up: leaves (t=8) then internal levels 7..0 ----
  level_kernel<0><<<(NTREE << DEPTH_) / NT, blk, 0, stream>>>(
      DEPTH_, X, W_bu, nullptr, b_bu, nullptr, nullptr, nullptr, h_bu, c_st);
  for (int t = DEPTH_ - 1; t >= 0; --t)
    level_kernel<1><<<(NTREE << t) / NT, blk, 0, stream>>>(
        t, X, W_bu, U_bu, b_bu, Uf_bu, bf_bu, nullptr, h_bu, c_st);

  // ---- top-down: root (t=0) then levels 1..8 ----
  level_kernel<2><<<NTREE / NT, blk, 0, stream>>>(
      0, X, W_td, nullptr, b_td, nullptr, nullptr, h_bu, h_td, c_st);
  for (int t = 1; t <= DEPTH_; ++t)
    level_kernel<3><<<(NTREE << t) / NT, blk, 0, stream>>>(
        t, X, W_td, U_td, b_td, Uf_td, bf_td, h_bu, h_td, c_st);

  // ---- output: [root h_bu | mean over leaves h_td] per tree ----
  finalize_kernel<<<NTREE, dim3(128), 0, stream>>>(h_bu, h_td, (float*)d_out);
}

// Round 2
// 713.707 us; speedup vs baseline: 3.3484x; 3.3484x over previous
//
#include <hip/hip_runtime.h>
#include <cmath>

#define NTREE 256
#define DEPTH_ 8
#define MPT 511                 // nodes per tree
#define NNODE (NTREE * MPT)     // 130816
#define HS 128

typedef __bf16 bf16x8 __attribute__((ext_vector_type(8)));
typedef float  f32x4  __attribute__((ext_vector_type(4)));

constexpr int NT = 32;   // nodes per block
constexpr int BT = 256;  // threads per block (4 waves)

__device__ __forceinline__ float sigf(float x) { return 1.0f / (1.0f + expf(-x)); }

__device__ __forceinline__ f32x4 mm(bf16x8 a, bf16x8 b, f32x4 c) {
  return __builtin_amdgcn_mfma_f32_16x16x32_bf16(a, b, c, 0, 0, 0);
}

// LDS tile helpers: row-major bf16 [rows][K], XOR-swizzled 16B chunks (T2)
__device__ __forceinline__ int swz_off(int row, int rowbytes, int kbyte) {
  return row * rowbytes + (kbyte ^ ((row & 7) << 4));
}
__device__ __forceinline__ void lds_store8(char* base, int row, int rowbytes, int chunk, bf16x8 v) {
  *reinterpret_cast<bf16x8*>(base + swz_off(row, rowbytes, chunk * 16)) = v;
}
__device__ __forceinline__ void cvt_store8(char* base, int row, int rowbytes, int chunk,
                                           float4 v0, float4 v1) {
  bf16x8 p;
  p[0] = (__bf16)v0.x; p[1] = (__bf16)v0.y; p[2] = (__bf16)v0.z; p[3] = (__bf16)v0.w;
  p[4] = (__bf16)v1.x; p[5] = (__bf16)v1.y; p[6] = (__bf16)v1.z; p[7] = (__bf16)v1.w;
  lds_store8(base, row, rowbytes, chunk, p);
}
__device__ __forceinline__ bf16x8 lds_a8(const char* base, int row, int rowbytes, int kbyte) {
  return *reinterpret_cast<const bf16x8*>(base + swz_off(row, rowbytes, kbyte));
}
__device__ __forceinline__ bf16x8 gld8(const __bf16* p) {
  return *reinterpret_cast<const bf16x8*>(p);
}

// MODE: 0 = BU leaf, 1 = BU internal, 2 = TD root, 3 = TD internal
template <int MODE>
__global__ void __launch_bounds__(BT)
level_kernel(int t,
             const float*  __restrict__ X,     // N x 128 f32
             const __bf16* __restrict__ Wcat,  // 384 x BK bf16 ([W|U] rows)
             int BK,
             const float*  __restrict__ bp,    // 384 f32
             const __bf16* __restrict__ Ufw,   // 128x128 bf16 (MODE 1,3)
             const float*  __restrict__ bfp,   // 128 f32
             const __bf16* __restrict__ hbu,   // N x 128 bf16 (MODE 2,3)
             __bf16* __restrict__ hout,        // h_bu (BU) / h_td (TD), bf16
             float*  __restrict__ cws)         // c state, f32
{
  constexpr int KA = (MODE == 0) ? 128 : (MODE == 3) ? 384 : 256;
  constexpr int A_BYTES = NT * KA * 2;
  constexpr int AUX = (MODE == 1) ? 17024 : 16;  // sCh 64x128 bf16 (16384) aliased by sCred 32x132 f32 (16896)

  __shared__ __align__(16) char sA[A_BYTES];
  __shared__ __align__(16) char sAux[AUX];
  __shared__ int sG[NT], sC[NT];

  const int tid = threadIdx.x;
  const int w = tid >> 6, l = tid & 63, lr = l & 15, lk = l >> 4;

  if (tid < NT) {
    int v = blockIdx.x * NT + tid;
    int b = v >> t;
    int j = ((1 << t) - 1) + (v & ((1 << t) - 1));
    int g = b * MPT + j;
    sG[tid] = g;
    int cc = 0;
    if (MODE == 1) cc = g + j + 1;                   // left child (right = +1)
    else if (MODE == 3) cc = b * MPT + ((j - 1) >> 1); // parent
    sC[tid] = cc;
  }
  __syncthreads();

  // ---------------- stage A into swizzled LDS (bf16) ----------------
  for (int idx = tid; idx < NT * 16; idx += BT) {     // X rows -> cols [0,128)
    int n = idx >> 4, e = idx & 15;
    const float4* src = reinterpret_cast<const float4*>(X + (size_t)sG[n] * HS) + e * 2;
    cvt_store8(sA, n, KA * 2, e, src[0], src[1]);
  }
  if constexpr (MODE == 2 || MODE == 3) {             // h_bu rows -> cols [128,256)
    for (int idx = tid; idx < NT * 16; idx += BT) {
      int n = idx >> 4, e = idx & 15;
      bf16x8 v = gld8(hbu + (size_t)sG[n] * HS + e * 8);
      lds_store8(sA, n, KA * 2, 16 + e, v);
    }
  }
  if constexpr (MODE == 3) {                          // h_td[parent] -> cols [256,384)
    for (int idx = tid; idx < NT * 16; idx += BT) {
      int n = idx >> 4, e = idx & 15;
      bf16x8 v = gld8(hout + (size_t)sC[n] * HS + e * 8);
      lds_store8(sA, n, KA * 2, 32 + e, v);
    }
  }
  if constexpr (MODE == 1) {                          // children rows + h_tild
    for (int idx = tid; idx < NT * 16; idx += BT) {
      int n = idx >> 4, e = idx & 15;
      bf16x8 hl = gld8(hout + (size_t)sC[n] * HS + e * 8);
      bf16x8 hr = gld8(hout + (size_t)(sC[n] + 1) * HS + e * 8);
      lds_store8(sAux, 2 * n,     HS * 2, e, hl);
      lds_store8(sAux, 2 * n + 1, HS * 2, e, hr);
      bf16x8 ht;
#pragma unroll
      for (int q = 0; q < 8; ++q) ht[q] = (__bf16)((float)hl[q] + (float)hr[q]);
      lds_store8(sA, n, KA * 2, 16 + e, ht);
    }
  }
  __syncthreads();

  // ---------------- forget-gate GEMM ----------------
  // wave w owns f-cols [32w, 32w+32)
  f32x4 faccC[4][2];   // MODE1: child rows (M=64), [cf][nfl]
  f32x4 facc3[2][2];   // MODE3: node rows (M=32),  [mf][nfl]
  if constexpr (MODE == 1) {
#pragma unroll
    for (int cf = 0; cf < 4; ++cf)
#pragma unroll
      for (int nfl = 0; nfl < 2; ++nfl) faccC[cf][nfl] = 0.0f;
#pragma unroll
    for (int ks = 0; ks < 4; ++ks) {
      bf16x8 a[4];
#pragma unroll
      for (int cf = 0; cf < 4; ++cf) a[cf] = lds_a8(sAux, 16 * cf + lr, HS * 2, ks * 64 + lk * 16);
#pragma unroll
      for (int nfl = 0; nfl < 2; ++nfl) {
        bf16x8 bb = gld8(Ufw + (size_t)(w * 32 + nfl * 16 + lr) * HS + ks * 32 + lk * 8);
#pragma unroll
        for (int cf = 0; cf < 4; ++cf) faccC[cf][nfl] = mm(a[cf], bb, faccC[cf][nfl]);
      }
    }
  }
  if constexpr (MODE == 3) {
#pragma unroll
    for (int mf = 0; mf < 2; ++mf)
#pragma unroll
      for (int nfl = 0; nfl < 2; ++nfl) facc3[mf][nfl] = 0.0f;
#pragma unroll
    for (int ks = 0; ks < 4; ++ks) {
      bf16x8 a0 = lds_a8(sA, lr,      KA * 2, 512 + ks * 64 + lk * 16);
      bf16x8 a1 = lds_a8(sA, 16 + lr, KA * 2, 512 + ks * 64 + lk * 16);
#pragma unroll
      for (int nfl = 0; nfl < 2; ++nfl) {
        bf16x8 bb = gld8(Ufw + (size_t)(w * 32 + nfl * 16 + lr) * HS + ks * 32 + lk * 8);
        facc3[0][nfl] = mm(a0, bb, facc3[0][nfl]);
        facc3[1][nfl] = mm(a1, bb, facc3[1][nfl]);
      }
    }
  }

  // MODE1: fc = sig(f)*c_child, pairwise-reduce to c_red, bounce via LDS (aliases sCh)
  float* sCred = reinterpret_cast<float*>(sAux);
  if constexpr (MODE == 1) {
    float crv[4][2][2];
#pragma unroll
    for (int cf = 0; cf < 4; ++cf)
#pragma unroll
      for (int nfl = 0; nfl < 2; ++nfl) {
        int ch = w * 32 + nfl * 16 + lr;
        float bfv = bfp[ch];
#pragma unroll
        for (int p = 0; p < 2; ++p) {
          float s = 0.0f;
#pragma unroll
          for (int q = 0; q < 2; ++q) {
            int j = 2 * p + q;
            int node = 8 * cf + lk * 2 + p;
            int gch = sC[node] + (j & 1);
            float f = sigf(faccC[cf][nfl][j] + bfv);
            s += f * cws[(size_t)gch * HS + ch];
          }
          crv[cf][nfl][p] = s;
        }
      }
    __syncthreads();  // all sCh reads done before aliased writes
#pragma unroll
    for (int cf = 0; cf < 4; ++cf)
#pragma unroll
      for (int nfl = 0; nfl < 2; ++nfl) {
        int ch = w * 32 + nfl * 16 + lr;
        sCred[(8 * cf + lk * 2)     * 132 + ch] = crv[cf][nfl][0];
        sCred[(8 * cf + lk * 2 + 1) * 132 + ch] = crv[cf][nfl][1];
      }
  }

  // ---------------- iou GEMM: 32 x 384, K = KA ----------------
  // wave w owns out-ch cols {32w..32w+32} for each of i/o/u
  f32x4 acc[3][2][2];  // [gate][nfl][mf]
#pragma unroll
  for (int g = 0; g < 3; ++g)
#pragma unroll
    for (int nfl = 0; nfl < 2; ++nfl)
#pragma unroll
      for (int mf = 0; mf < 2; ++mf) acc[g][nfl][mf] = 0.0f;

#pragma unroll
  for (int ks = 0; ks < KA / 32; ++ks) {
    bf16x8 a0 = lds_a8(sA, lr,      KA * 2, ks * 64 + lk * 16);
    bf16x8 a1 = lds_a8(sA, 16 + lr, KA * 2, ks * 64 + lk * 16);
    int kofs = ks * 32 + lk * 8;
#pragma unroll
    for (int g = 0; g < 3; ++g)
#pragma unroll
      for (int nfl = 0; nfl < 2; ++nfl) {
        int oc = g * 128 + w * 32 + nfl * 16 + lr;
        bf16x8 bb = gld8(Wcat + (size_t)oc * BK + kofs);
        acc[g][nfl][0] = mm(a0, bb, acc[g][nfl][0]);
        acc[g][nfl][1] = mm(a1, bb, acc[g][nfl][1]);
      }
  }

  if constexpr (MODE == 1) __syncthreads();  // sCred visible before gate

  // ---------------- gating (in-register; C-layout col=lane&15, row=(lane>>4)*4+reg) ---
#pragma unroll
  for (int nfl = 0; nfl < 2; ++nfl) {
    int ch = w * 32 + nfl * 16 + lr;
    float bi = bp[ch], bo = bp[ch + 128], bu = bp[ch + 256];
    float bfv = 0.0f;
    if constexpr (MODE == 3) bfv = bfp[ch];
#pragma unroll
    for (int mf = 0; mf < 2; ++mf) {
#pragma unroll
      for (int j = 0; j < 4; ++j) {
        int nrow = 16 * mf + lk * 4 + j;
        int g = sG[nrow];
        float iv = acc[0][nfl][mf][j] + bi;
        float ov = acc[1][nfl][mf][j] + bo;
        float uv = acc[2][nfl][mf][j] + bu;
        float cbase = 0.0f;
        if constexpr (MODE == 1) cbase = sCred[nrow * 132 + ch];
        if constexpr (MODE == 3) {
          float fp = facc3[mf][nfl][j] + bfv;
          cbase = sigf(fp) * cws[(size_t)sC[nrow] * HS + ch];
        }
        float cn = sigf(iv) * tanhf(uv) + cbase;
        float hn = sigf(ov) * tanhf(cn);
        size_t o = (size_t)g * HS + ch;
        hout[o] = (__bf16)hn;
        cws[o]  = cn;
      }
    }
  }
}

// convert + concat two f32 matrices row-wise into bf16 [rows][ka+kb]
__global__ void __launch_bounds__(256)
cvt_cat(const float* __restrict__ A, int ka,
        const float* __restrict__ Bs, int kb,
        int rows, __bf16* __restrict__ dst)
{
  int k = ka + kb, total = rows * k;
  for (int i = blockIdx.x * blockDim.x + threadIdx.x; i < total; i += gridDim.x * blockDim.x) {
    int r = i / k, c = i - r * k;
    float v = (c < ka) ? A[(size_t)r * ka + c] : Bs[(size_t)r * kb + (c - ka)];
    dst[i] = (__bf16)v;
  }
}

__global__ void __launch_bounds__(128)
finalize_kernel(const __bf16* __restrict__ h_bu, const __bf16* __restrict__ h_td,
                float* __restrict__ out)
{
  int b = blockIdx.x, ch = threadIdx.x;
  out[(size_t)b * 256 + ch] = (float)h_bu[((size_t)b * MPT) * HS + ch];
  const __bf16* base = h_td + ((size_t)b * MPT + 255) * HS + ch;  // leaves j in [255,511)
  float s = 0.0f;
#pragma unroll 8
  for (int l = 0; l < 256; ++l) s += (float)base[(size_t)l * HS];
  out[(size_t)b * 256 + 128 + ch] = s * (1.0f / 256.0f);
}

extern "C" void kernel_launch(void* const* d_in, const int* in_sizes, int n_in,
                              void* d_out, int out_size, void* d_ws, size_t ws_size,
                              hipStream_t stream) {
  const float* X     = (const float*)d_in[0];
  const float* W_bu  = (const float*)d_in[3];
  const float* U_bu  = (const float*)d_in[4];
  const float* b_bu  = (const float*)d_in[5];
  const float* Uf_bu = (const float*)d_in[6];
  const float* bf_bu = (const float*)d_in[7];
  const float* W_td  = (const float*)d_in[8];
  const float* U_td  = (const float*)d_in[9];
  const float* b_td  = (const float*)d_in[10];
  const float* Uf_td = (const float*)d_in[11];
  const float* bf_td = (const float*)d_in[12];

  // workspace: bf16 weights (0.56 MB) | h_bu bf16 | h_td bf16 | c f32  = 134.5 MB total
  char* p = (char*)d_ws;
  __bf16* wbu  = (__bf16*)p; p += (size_t)384 * 256 * 2;
  __bf16* wtd  = (__bf16*)p; p += (size_t)384 * 384 * 2;
  __bf16* ufb  = (__bf16*)p; p += (size_t)128 * 128 * 2;
  __bf16* uft  = (__bf16*)p; p += (size_t)128 * 128 * 2;
  __bf16* h_bu = (__bf16*)p; p += (size_t)NNODE * HS * 2;
  __bf16* h_td = (__bf16*)p; p += (size_t)NNODE * HS * 2;
  float*  c_st = (float*)p;

  // ---- weight conversion to bf16 (concatenated [W|U] rows) ----
  cvt_cat<<<128, 256, 0, stream>>>(W_bu, 128, U_bu, 128, 384, wbu);
  cvt_cat<<<128, 256, 0, stream>>>(W_td, 256, U_td, 128, 384, wtd);
  cvt_cat<<<32, 256, 0, stream>>>(Uf_bu, 128, Uf_bu, 0, 128, ufb);
  cvt_cat<<<32, 256, 0, stream>>>(Uf_td, 128, Uf_td, 0, 128, uft);

  dim3 blk(BT);

  // ---- bottom-up: leaves (t=8) then internal 7..0 ----
  level_kernel<0><<<(NTREE << DEPTH_) / NT, blk, 0, stream>>>(
      DEPTH_, X, wbu, 256, b_bu, nullptr, nullptr, nullptr, h_bu, c_st);
  for (int t = DEPTH_ - 1; t >= 0; --t)
    level_kernel<1><<<(NTREE << t) / NT, blk, 0, stream>>>(
        t, X, wbu, 256, b_bu, ufb, bf_bu, nullptr, h_bu, c_st);

  // ---- top-down: root (t=0) then 1..8 ----
  level_kernel<2><<<NTREE / NT, blk, 0, stream>>>(
      0, X, wtd, 384, b_td, nullptr, nullptr, h_bu, h_td, c_st);
  for (int t = 1; t <= DEPTH_; ++t)
    level_kernel<3><<<(NTREE << t) / NT, blk, 0, stream>>>(
        t, X, wtd, 384, b_td, uft, bf_td, h_bu, h_td, c_st);

  // ---- output: [root h_bu | mean over leaves h_td] per tree ----
  finalize_kernel<<<NTREE, dim3(128), 0, stream>>>(h_bu, h_td, (float*)d_out);
}

// Round 3
// 632.631 us; speedup vs baseline: 3.7776x; 1.1282x over previous
//
#include <hip/hip_runtime.h>
#include <cmath>

#define NTREE 256
#define MPT 511
#define NNODE (NTREE * MPT)   // 130816
#define HS 128

typedef __bf16 bf16x8 __attribute__((ext_vector_type(8)));
typedef float  f32x4  __attribute__((ext_vector_type(4)));

__device__ __forceinline__ float sigf(float x) { return 1.0f / (1.0f + expf(-x)); }
__device__ __forceinline__ f32x4 mm(bf16x8 a, bf16x8 b, f32x4 c) {
  return __builtin_amdgcn_mfma_f32_16x16x32_bf16(a, b, c, 0, 0, 0);
}
// XOR-swizzled LDS tile helpers (T2): row-major bf16, 16B chunk swizzle
__device__ __forceinline__ int swz(int row, int rb, int kb) { return row * rb + (kb ^ ((row & 7) << 4)); }
__device__ __forceinline__ void st8(char* s, int row, int rb, int chunk, bf16x8 v) {
  *reinterpret_cast<bf16x8*>(s + swz(row, rb, chunk * 16)) = v;
}
__device__ __forceinline__ bf16x8 ld8(const char* s, int row, int rb, int kb) {
  return *reinterpret_cast<const bf16x8*>(s + swz(row, rb, kb));
}
__device__ __forceinline__ bf16x8 g8(const __bf16* p) { return *reinterpret_cast<const bf16x8*>(p); }
__device__ __forceinline__ void stbf(char* s, int row, int rb, int kbyte, float v) {
  *reinterpret_cast<__bf16*>(s + row * rb + (kbyte ^ ((row & 7) << 4))) = (__bf16)v;
}

// ---------------------------------------------------------------------------
// Big-level kernel: 64 nodes/block, 4 waves; wave w owns out-channels
// [32w,32w+32) of each of i/o/u (and f in epilogue).
// MODE: 0 = BU leaf (K=128), 1 = BU internal (K=256), 3 = TD (K=384)
// EPI: compute f for this level's nodes and push cred/htild (BU) or fc (TD)
// ---------------------------------------------------------------------------
template <int MODE, bool EPI>
__global__ void __launch_bounds__(256, 2)
level_big(int t,
          const __bf16* __restrict__ Xb,
          const __bf16* __restrict__ W,   // [384][BK] bf16
          const float*  __restrict__ bp,  // 384
          const __bf16* __restrict__ Uf,  // [128][128] bf16
          const float*  __restrict__ bf_, // 128
          __bf16* __restrict__ h_bu,
          __bf16* __restrict__ h_td,
          float*  __restrict__ cws)
{
  constexpr int KA = (MODE == 0) ? 128 : (MODE == 1) ? 256 : 384;
  constexpr int KS = KA / 32;
  constexpr int BK = (MODE == 3) ? 384 : 256;
  constexpr int RB = KA * 2;                                  // LDS row bytes
  constexpr int HB = (MODE == 0) ? 0 : (MODE == 1) ? 256 : 512; // h-bounce byte offset

  __shared__ __align__(16) char sA[64 * RB];
  __shared__ int sG[64], sP[64];

  const int tid = threadIdx.x;
  const int w = tid >> 6, l = tid & 63, lr = l & 15, lk = l >> 4;

  if (tid < 64) {
    int v = blockIdx.x * 64 + tid;
    int b = v >> t;
    int j = (1 << t) - 1 + (v & ((1 << t) - 1));
    sG[tid] = b * MPT + j;
    sP[tid] = b * MPT + ((j - 1) >> 1);
  }
  __syncthreads();

  // ---- stage A = [Xb | (htild/h_bu) | (h_td parent)] into swizzled LDS ----
#pragma unroll
  for (int it = 0; it < 4; ++it) {
    int idx = tid + it * 256, n = idx >> 4, e = idx & 15;
    st8(sA, n, RB, e, g8(Xb + (size_t)sG[n] * HS + e * 8));
  }
  if constexpr (MODE >= 1) {
#pragma unroll
    for (int it = 0; it < 4; ++it) {
      int idx = tid + it * 256, n = idx >> 4, e = idx & 15;
      st8(sA, n, RB, 16 + e, g8(h_bu + (size_t)sG[n] * HS + e * 8));
    }
  }
  if constexpr (MODE == 3) {
#pragma unroll
    for (int it = 0; it < 4; ++it) {
      int idx = tid + it * 256, n = idx >> 4, e = idx & 15;
      st8(sA, n, RB, 32 + e, g8(h_td + (size_t)sP[n] * HS + e * 8));
    }
  }
  __syncthreads();

  // ---- iou GEMM: 64 x 384, K = KA ----
  f32x4 acc[3][2][4];
#pragma unroll
  for (int g2 = 0; g2 < 3; ++g2)
#pragma unroll
    for (int nf = 0; nf < 2; ++nf)
#pragma unroll
      for (int mf = 0; mf < 4; ++mf) acc[g2][nf][mf] = 0.0f;

#pragma unroll
  for (int ks = 0; ks < KS; ++ks) {
    bf16x8 a0 = ld8(sA, lr,      RB, ks * 64 + lk * 16);
    bf16x8 a1 = ld8(sA, 16 + lr, RB, ks * 64 + lk * 16);
    bf16x8 a2 = ld8(sA, 32 + lr, RB, ks * 64 + lk * 16);
    bf16x8 a3 = ld8(sA, 48 + lr, RB, ks * 64 + lk * 16);
#pragma unroll
    for (int g2 = 0; g2 < 3; ++g2)
#pragma unroll
      for (int nf = 0; nf < 2; ++nf) {
        bf16x8 bb = g8(W + (size_t)(g2 * 128 + w * 32 + nf * 16 + lr) * BK + ks * 32 + lk * 8);
        acc[g2][nf][0] = mm(a0, bb, acc[g2][nf][0]);
        acc[g2][nf][1] = mm(a1, bb, acc[g2][nf][1]);
        acc[g2][nf][2] = mm(a2, bb, acc[g2][nf][2]);
        acc[g2][nf][3] = mm(a3, bb, acc[g2][nf][3]);
      }
  }

  // ---- gating (C layout: row = 16mf + lk*4 + j, col = lr) ----
  __bf16* hp = (MODE == 3) ? h_td : h_bu;
  float cnv[2][4][4], hnv[2][4][4];
#pragma unroll
  for (int nf = 0; nf < 2; ++nf) {
    const int ch = w * 32 + nf * 16 + lr;
    const float bi = bp[ch], bo = bp[ch + 128], bu_ = bp[ch + 256];
#pragma unroll
    for (int mf = 0; mf < 4; ++mf)
#pragma unroll
      for (int j = 0; j < 4; ++j) {
        const int nrow = 16 * mf + lk * 4 + j;
        float cb = 0.0f;
        if constexpr (MODE == 1) cb = cws[(size_t)sG[nrow] * HS + ch];
        if constexpr (MODE == 3) cb = cws[(size_t)sP[nrow] * HS + ch];
        float cn = sigf(acc[0][nf][mf][j] + bi) * tanhf(acc[2][nf][mf][j] + bu_) + cb;
        float hn = sigf(acc[1][nf][mf][j] + bo) * tanhf(cn);
        hp[(size_t)sG[nrow] * HS + ch] = (__bf16)hn;
        cnv[nf][mf][j] = cn; hnv[nf][mf][j] = hn;
      }
  }

  // ---- epilogue: f = sig(Uf h + bf); push to parents (BU) / own row (TD) ----
  if constexpr (EPI) {
    __syncthreads();  // all GEMM reads of sA done before bounce overwrite
#pragma unroll
    for (int nf = 0; nf < 2; ++nf) {
      const int ch = w * 32 + nf * 16 + lr;
#pragma unroll
      for (int mf = 0; mf < 4; ++mf)
#pragma unroll
        for (int j = 0; j < 4; ++j)
          stbf(sA, 16 * mf + lk * 4 + j, RB, HB + 2 * ch, hnv[nf][mf][j]);
    }
    __syncthreads();
    f32x4 fa[4][2];
#pragma unroll
    for (int mf = 0; mf < 4; ++mf) { fa[mf][0] = 0.0f; fa[mf][1] = 0.0f; }
#pragma unroll
    for (int ks = 0; ks < 4; ++ks) {
      bf16x8 a0 = ld8(sA, lr,      RB, HB + ks * 64 + lk * 16);
      bf16x8 a1 = ld8(sA, 16 + lr, RB, HB + ks * 64 + lk * 16);
      bf16x8 a2 = ld8(sA, 32 + lr, RB, HB + ks * 64 + lk * 16);
      bf16x8 a3 = ld8(sA, 48 + lr, RB, HB + ks * 64 + lk * 16);
#pragma unroll
      for (int nf = 0; nf < 2; ++nf) {
        bf16x8 bb = g8(Uf + (size_t)(w * 32 + nf * 16 + lr) * HS + ks * 32 + lk * 8);
        fa[0][nf] = mm(a0, bb, fa[0][nf]);
        fa[1][nf] = mm(a1, bb, fa[1][nf]);
        fa[2][nf] = mm(a2, bb, fa[2][nf]);
        fa[3][nf] = mm(a3, bb, fa[3][nf]);
      }
    }
#pragma unroll
    for (int nf = 0; nf < 2; ++nf) {
      const int ch = w * 32 + nf * 16 + lr;
      const float bfv = bf_[ch];
      if constexpr (MODE == 3) {
#pragma unroll
        for (int mf = 0; mf < 4; ++mf)
#pragma unroll
          for (int j = 0; j < 4; ++j) {
            const int nrow = 16 * mf + lk * 4 + j;
            cws[(size_t)sG[nrow] * HS + ch] = sigf(fa[mf][nf][j] + bfv) * cnv[nf][mf][j];
          }
      } else {
#pragma unroll
        for (int mf = 0; mf < 4; ++mf)
#pragma unroll
          for (int p = 0; p < 2; ++p) {
            const int er = 16 * mf + lk * 4 + 2 * p;  // even sibling row
            float f0 = sigf(fa[mf][nf][2 * p]     + bfv) * cnv[nf][mf][2 * p];
            float f1 = sigf(fa[mf][nf][2 * p + 1] + bfv) * cnv[nf][mf][2 * p + 1];
            const int gp = sP[er];
            cws[(size_t)gp * HS + ch] = f0 + f1;                                   // c_red
            h_bu[(size_t)gp * HS + ch] = (__bf16)(hnv[nf][mf][2 * p] + hnv[nf][mf][2 * p + 1]); // htild
          }
      }
    }
  }
}

// ---------------------------------------------------------------------------
// BU small levels t=4..0, one block per tree; state (cred/htild) kept in LDS.
// ---------------------------------------------------------------------------
__global__ void __launch_bounds__(256)
bu_small(const __bf16* __restrict__ Xb, const __bf16* __restrict__ W,
         const float* __restrict__ bp, const __bf16* __restrict__ Uf,
         const float* __restrict__ bf_, __bf16* __restrict__ h_bu,
         const float* __restrict__ cws)
{
  __shared__ __align__(16) char sA[16 * 512];  // [16][256] bf16 swz
  __shared__ float sCr[16][HS];
  __shared__ int sG[16];
  const int tid = threadIdx.x, w = tid >> 6, l = tid & 63, lr = l & 15, lk = l >> 4;
  const int b = blockIdx.x;
  const int n = tid >> 4, e = tid & 15;

  for (int t = 4; t >= 0; --t) {
    const int cnt = 1 << t, j0 = cnt - 1;
    if (tid < 16) { int r = tid < cnt ? tid : cnt - 1; sG[tid] = b * MPT + j0 + r; }
    __syncthreads();
    st8(sA, n, 512, e, g8(Xb + (size_t)sG[n] * HS + e * 8));
    if (t == 4) st8(sA, n, 512, 16 + e, g8(h_bu + (size_t)sG[n] * HS + e * 8));
    __syncthreads();

    f32x4 acc[3][2];
#pragma unroll
    for (int g2 = 0; g2 < 3; ++g2) { acc[g2][0] = 0.0f; acc[g2][1] = 0.0f; }
#pragma unroll
    for (int ks = 0; ks < 8; ++ks) {
      bf16x8 a0 = ld8(sA, lr, 512, ks * 64 + lk * 16);
#pragma unroll
      for (int g2 = 0; g2 < 3; ++g2)
#pragma unroll
        for (int nf = 0; nf < 2; ++nf) {
          bf16x8 bb = g8(W + (size_t)(g2 * 128 + w * 32 + nf * 16 + lr) * 256 + ks * 32 + lk * 8);
          acc[g2][nf] = mm(a0, bb, acc[g2][nf]);
        }
    }
    float cnv[2][4], hnv[2][4];
#pragma unroll
    for (int nf = 0; nf < 2; ++nf) {
      const int ch = w * 32 + nf * 16 + lr;
      const float bi = bp[ch], bo = bp[ch + 128], bu_ = bp[ch + 256];
#pragma unroll
      for (int j = 0; j < 4; ++j) {
        int r = lk * 4 + j;
        float cb = (t == 4) ? cws[(size_t)sG[r] * HS + ch] : sCr[r][ch];
        float cn = sigf(acc[0][nf][j] + bi) * tanhf(acc[2][nf][j] + bu_) + cb;
        float hn = sigf(acc[1][nf][j] + bo) * tanhf(cn);
        if (r < cnt) h_bu[(size_t)sG[r] * HS + ch] = (__bf16)hn;
        cnv[nf][j] = cn; hnv[nf][j] = hn;
      }
    }
    if (t > 0) {
      __syncthreads();
#pragma unroll
      for (int nf = 0; nf < 2; ++nf) {
        const int ch = w * 32 + nf * 16 + lr;
#pragma unroll
        for (int j = 0; j < 4; ++j) stbf(sA, lk * 4 + j, 512, 2 * ch, hnv[nf][j]);
      }
      __syncthreads();
      f32x4 fa[2]; fa[0] = 0.0f; fa[1] = 0.0f;
#pragma unroll
      for (int ks = 0; ks < 4; ++ks) {
        bf16x8 a0 = ld8(sA, lr, 512, ks * 64 + lk * 16);
#pragma unroll
        for (int nf = 0; nf < 2; ++nf) {
          bf16x8 bb = g8(Uf + (size_t)(w * 32 + nf * 16 + lr) * HS + ks * 32 + lk * 8);
          fa[nf] = mm(a0, bb, fa[nf]);
        }
      }
#pragma unroll
      for (int nf = 0; nf < 2; ++nf) {
        const int ch = w * 32 + nf * 16 + lr;
        const float bfv = bf_[ch];
#pragma unroll
        for (int p = 0; p < 2; ++p) {
          int pr = lk * 2 + p;
          if (pr < (cnt >> 1)) {
            float f0 = sigf(fa[nf][2 * p]     + bfv) * cnv[nf][2 * p];
            float f1 = sigf(fa[nf][2 * p + 1] + bfv) * cnv[nf][2 * p + 1];
            sCr[pr][ch] = f0 + f1;
            stbf(sA, pr, 512, 2 * (128 + ch), hnv[nf][2 * p] + hnv[nf][2 * p + 1]);
          }
        }
      }
      __syncthreads();
    }
  }
}

// ---------------------------------------------------------------------------
// TD small levels t=0..4, one block per tree; h/fc state in LDS.
// ---------------------------------------------------------------------------
__global__ void __launch_bounds__(256)
td_small(const __bf16* __restrict__ Xb, const __bf16* __restrict__ W,
         const float* __restrict__ bp, const __bf16* __restrict__ Uf,
         const float* __restrict__ bf_, const __bf16* __restrict__ h_bu,
         __bf16* __restrict__ h_td, float* __restrict__ cws)
{
  __shared__ __align__(16) char sA[16 * 768];   // [16][384] bf16 swz
  __shared__ __align__(16) char sHt[16 * 256];  // [16][128] bf16 swz (h_td state)
  __shared__ float sFc[16][HS];
  __shared__ int sG[16];
  const int tid = threadIdx.x, w = tid >> 6, l = tid & 63, lr = l & 15, lk = l >> 4;
  const int b = blockIdx.x;
  const int n = tid >> 4, e = tid & 15;

  for (int t = 0; t <= 4; ++t) {
    const int cnt = 1 << t, j0 = cnt - 1;
    if (tid < 16) { int r = tid < cnt ? tid : cnt - 1; sG[tid] = b * MPT + j0 + r; }
    __syncthreads();
    st8(sA, n, 768, e,      g8(Xb   + (size_t)sG[n] * HS + e * 8));
    st8(sA, n, 768, 16 + e, g8(h_bu + (size_t)sG[n] * HS + e * 8));
    if (t > 0) { bf16x8 v = ld8(sHt, n >> 1, 256, e * 16); st8(sA, n, 768, 32 + e, v); }
    __syncthreads();

    f32x4 acc[3][2];
#pragma unroll
    for (int g2 = 0; g2 < 3; ++g2) { acc[g2][0] = 0.0f; acc[g2][1] = 0.0f; }
    auto step = [&](int ks) {
      bf16x8 a0 = ld8(sA, lr, 768, ks * 64 + lk * 16);
#pragma unroll
      for (int g2 = 0; g2 < 3; ++g2)
#pragma unroll
        for (int nf = 0; nf < 2; ++nf) {
          bf16x8 bb = g8(W + (size_t)(g2 * 128 + w * 32 + nf * 16 + lr) * 384 + ks * 32 + lk * 8);
          acc[g2][nf] = mm(a0, bb, acc[g2][nf]);
        }
    };
#pragma unroll
    for (int ks = 0; ks < 8; ++ks) step(ks);
    if (t > 0) {
#pragma unroll
      for (int ks = 8; ks < 12; ++ks) step(ks);
    }

    float cnv[2][4], hnv[2][4];
#pragma unroll
    for (int nf = 0; nf < 2; ++nf) {
      const int ch = w * 32 + nf * 16 + lr;
      const float bi = bp[ch], bo = bp[ch + 128], bu_ = bp[ch + 256];
#pragma unroll
      for (int j = 0; j < 4; ++j) {
        int r = lk * 4 + j;
        float cb = (t == 0) ? 0.0f : sFc[r >> 1][ch];
        float cn = sigf(acc[0][nf][j] + bi) * tanhf(acc[2][nf][j] + bu_) + cb;
        float hn = sigf(acc[1][nf][j] + bo) * tanhf(cn);
        if (r < cnt) h_td[(size_t)sG[r] * HS + ch] = (__bf16)hn;
        cnv[nf][j] = cn; hnv[nf][j] = hn;
      }
    }
    // epilogue: fc for children of this level
    __syncthreads();
#pragma unroll
    for (int nf = 0; nf < 2; ++nf) {
      const int ch = w * 32 + nf * 16 + lr;
#pragma unroll
      for (int j = 0; j < 4; ++j) stbf(sHt, lk * 4 + j, 256, 2 * ch, hnv[nf][j]);
    }
    __syncthreads();
    f32x4 fa[2]; fa[0] = 0.0f; fa[1] = 0.0f;
#pragma unroll
    for (int ks = 0; ks < 4; ++ks) {
      bf16x8 a0 = ld8(sHt, lr, 256, ks * 64 + lk * 16);
#pragma unroll
      for (int nf = 0; nf < 2; ++nf) {
        bf16x8 bb = g8(Uf + (size_t)(w * 32 + nf * 16 + lr) * HS + ks * 32 + lk * 8);
        fa[nf] = mm(a0, bb, fa[nf]);
      }
    }
#pragma unroll
    for (int nf = 0; nf < 2; ++nf) {
      const int ch = w * 32 + nf * 16 + lr;
      const float bfv = bf_[ch];
#pragma unroll
      for (int j = 0; j < 4; ++j) {
        int r = lk * 4 + j;
        float fc = sigf(fa[nf][j] + bfv) * cnv[nf][j];
        if (r < cnt) {
          if (t < 4) sFc[r][ch] = fc;
          else       cws[(size_t)sG[r] * HS + ch] = fc;
        }
      }
    }
    __syncthreads();
  }
}

// ---------------------------------------------------------------------------
__global__ void __launch_bounds__(256)
prep(const float* __restrict__ Wbu, const float* __restrict__ Ubu,
     const float* __restrict__ Wtd, const float* __restrict__ Utd,
     const float* __restrict__ Ufb, const float* __restrict__ Uft,
     __bf16* wbu, __bf16* wtd, __bf16* ufb, __bf16* uft)
{
  int i = blockIdx.x * 256 + threadIdx.x;
  if (i < 98304) {
    int r = i >> 8, c = i & 255;
    wbu[i] = (__bf16)(c < 128 ? Wbu[r * 128 + c] : Ubu[r * 128 + c - 128]);
  } else if (i < 245760) {
    int k = i - 98304; int r = k / 384, c = k - r * 384;
    wtd[k] = (__bf16)(c < 256 ? Wtd[r * 256 + c] : Utd[r * 128 + (c - 256)]);
  } else if (i < 262144) {
    int k = i - 245760; ufb[k] = (__bf16)Ufb[k];
  } else {
    int k = i - 262144; uft[k] = (__bf16)Uft[k];
  }
}

__global__ void __launch_bounds__(256)
cvtX_k(const float* __restrict__ X, __bf16* __restrict__ Xb)
{
  for (size_t idx = blockIdx.x * 256 + threadIdx.x; idx < (size_t)NNODE * 16;
       idx += (size_t)2048 * 256) {
    float4 v0 = reinterpret_cast<const float4*>(X)[idx * 2];
    float4 v1 = reinterpret_cast<const float4*>(X)[idx * 2 + 1];
    bf16x8 o;
    o[0] = (__bf16)v0.x; o[1] = (__bf16)v0.y; o[2] = (__bf16)v0.z; o[3] = (__bf16)v0.w;
    o[4] = (__bf16)v1.x; o[5] = (__bf16)v1.y; o[6] = (__bf16)v1.z; o[7] = (__bf16)v1.w;
    reinterpret_cast<bf16x8*>(Xb)[idx] = o;
  }
}

__global__ void __launch_bounds__(128)
finalize_kernel(const __bf16* __restrict__ h_bu, const __bf16* __restrict__ h_td,
                float* __restrict__ out)
{
  int b = blockIdx.x, ch = threadIdx.x;
  out[(size_t)b * 256 + ch] = (float)h_bu[((size_t)b * MPT) * HS + ch];
  const __bf16* base = h_td + ((size_t)b * MPT + 255) * HS + ch;
  float s = 0.0f;
#pragma unroll 8
  for (int l = 0; l < 256; ++l) s += (float)base[(size_t)l * HS];
  out[(size_t)b * 256 + 128 + ch] = s * (1.0f / 256.0f);
}

extern "C" void kernel_launch(void* const* d_in, const int* in_sizes, int n_in,
                              void* d_out, int out_size, void* d_ws, size_t ws_size,
                              hipStream_t stream) {
  const float* X     = (const float*)d_in[0];
  const float* W_bu  = (const float*)d_in[3];
  const float* U_bu  = (const float*)d_in[4];
  const float* b_bu  = (const float*)d_in[5];
  const float* Uf_bu = (const float*)d_in[6];
  const float* bf_bu = (const float*)d_in[7];
  const float* W_td  = (const float*)d_in[8];
  const float* U_td  = (const float*)d_in[9];
  const float* b_td  = (const float*)d_in[10];
  const float* Uf_td = (const float*)d_in[11];
  const float* bf_td = (const float*)d_in[12];

  // ws: weights 0.53MB | Xb | h_bu | h_td (bf16, 33.5MB each) | cws f32 67MB ≈ 168MB
  char* p = (char*)d_ws;
  __bf16* wbu  = (__bf16*)p; p += (size_t)384 * 256 * 2;
  __bf16* wtd  = (__bf16*)p; p += (size_t)384 * 384 * 2;
  __bf16* ufb  = (__bf16*)p; p += (size_t)128 * 128 * 2;
  __bf16* uft  = (__bf16*)p; p += (size_t)128 * 128 * 2;
  __bf16* Xb   = (__bf16*)p; p += (size_t)NNODE * HS * 2;
  __bf16* h_bu = (__bf16*)p; p += (size_t)NNODE * HS * 2;
  __bf16* h_td = (__bf16*)p; p += (size_t)NNODE * HS * 2;
  float*  cws  = (float*)p;

  prep<<<1088, 256, 0, stream>>>(W_bu, U_bu, W_td, U_td, Uf_bu, Uf_td, wbu, wtd, ufb, uft);
  cvtX_k<<<2048, 256, 0, stream>>>(X, Xb);

  // bottom-up
  level_big<0, true><<<1024, 256, 0, stream>>>(8, Xb, wbu, b_bu, ufb, bf_bu, h_bu, h_td, cws);
  level_big<1, true><<<512,  256, 0, stream>>>(7, Xb, wbu, b_bu, ufb, bf_bu, h_bu, h_td, cws);
  level_big<1, true><<<256,  256, 0, stream>>>(6, Xb, wbu, b_bu, ufb, bf_bu, h_bu, h_td, cws);
  level_big<1, true><<<128,  256, 0, stream>>>(5, Xb, wbu, b_bu, ufb, bf_bu, h_bu, h_td, cws);
  bu_small<<<256, 256, 0, stream>>>(Xb, wbu, b_bu, ufb, bf_bu, h_bu, cws);

  // top-down
  td_small<<<256, 256, 0, stream>>>(Xb, wtd, b_td, uft, bf_td, h_bu, h_td, cws);
  level_big<3, true ><<<128,  256, 0, stream>>>(5, Xb, wtd, b_td, uft, bf_td, h_bu, h_td, cws);
  level_big<3, true ><<<256,  256, 0, stream>>>(6, Xb, wtd, b_td, uft, bf_td, h_bu, h_td, cws);
  level_big<3, true ><<<512,  256, 0, stream>>>(7, Xb, wtd, b_td, uft, bf_td, h_bu, h_td, cws);
  level_big<3, false><<<1024, 256, 0, stream>>>(8, Xb, wtd, b_td, uft, bf_td, h_bu, h_td, cws);

  finalize_kernel<<<256, 128, 0, stream>>>(h_bu, h_td, (float*)d_out);
}

// Round 4
// 396.475 us; speedup vs baseline: 6.0276x; 1.5956x over previous
//
#include <hip/hip_runtime.h>
#include <cmath>

#define NTREE 256
#define MPT 511
#define NNODE (NTREE * MPT)   // 130816
#define HS 128

typedef __bf16 bf16x8 __attribute__((ext_vector_type(8)));
typedef float  f32x4  __attribute__((ext_vector_type(4)));

__device__ __forceinline__ float sigf(float x) {
  float e = __builtin_amdgcn_exp2f(x * -1.44269504f);
  return __builtin_amdgcn_rcpf(1.0f + e);
}
__device__ __forceinline__ float tanh_fast(float x) {
  float e = __builtin_amdgcn_exp2f(x * -2.88539008f);
  return __builtin_amdgcn_rcpf(1.0f + e) * 2.0f - 1.0f;
}
__device__ __forceinline__ f32x4 mm(bf16x8 a, bf16x8 b, f32x4 c) {
  return __builtin_amdgcn_mfma_f32_16x16x32_bf16(a, b, c, 0, 0, 0);
}
// XOR-swizzled LDS tile helpers (T2): row-major bf16, 16B chunk swizzle
__device__ __forceinline__ int swz(int row, int rb, int kb) { return row * rb + (kb ^ ((row & 7) << 4)); }
__device__ __forceinline__ void st8(char* s, int row, int rb, int chunk, bf16x8 v) {
  *reinterpret_cast<bf16x8*>(s + swz(row, rb, chunk * 16)) = v;
}
__device__ __forceinline__ bf16x8 ld8(const char* s, int row, int rb, int kb) {
  return *reinterpret_cast<const bf16x8*>(s + swz(row, rb, kb));
}
__device__ __forceinline__ bf16x8 g8(const __bf16* p) { return *reinterpret_cast<const bf16x8*>(p); }
__device__ __forceinline__ void stbf(char* s, int row, int rb, int kbyte, float v) {
  *reinterpret_cast<__bf16*>(s + row * rb + (kbyte ^ ((row & 7) << 4))) = (__bf16)v;
}

// ---------------------------------------------------------------------------
// Big-level kernel: 64 nodes/block, 4 waves; wave w owns out-channels
// [32w,32w+32) of each of i/o/u (and f in epilogue).
// MODE: 0 = BU leaf (K=128), 1 = BU internal (K=256), 3 = TD (K=384)
// EPI: compute f for this level and push cred/htild (BU) or fc (TD).
// MODE3 && !EPI (TD leaves): no h_td store; in-register leaf-sum -> part.
// ---------------------------------------------------------------------------
template <int MODE, bool EPI>
__global__ void __launch_bounds__(256, 2)
level_big(int t,
          const __bf16* __restrict__ Xb,
          const __bf16* __restrict__ W,   // [384][BK] bf16
          const float*  __restrict__ bp,  // 384
          const __bf16* __restrict__ Uf,  // [128][128] bf16
          const float*  __restrict__ bf_, // 128
          __bf16* __restrict__ h_bu,
          __bf16* __restrict__ h_td,
          float*  __restrict__ cws,
          float*  __restrict__ part)
{
  constexpr int KA = (MODE == 0) ? 128 : (MODE == 1) ? 256 : 384;
  constexpr int KS = KA / 32;
  constexpr int BK = (MODE == 3) ? 384 : 256;
  constexpr int RB = KA * 2;
  constexpr int HB = (MODE == 0) ? 0 : (MODE == 1) ? 256 : 512;
  constexpr bool LEAFOUT = (MODE == 3 && !EPI);

  __shared__ __align__(16) char sA[64 * RB];
  __shared__ int sG[64], sP[64];

  const int tid = threadIdx.x;
  const int w = tid >> 6, l = tid & 63, lr = l & 15, lk = l >> 4;

  if (tid < 64) {
    int v = blockIdx.x * 64 + tid;
    int b = v >> t;
    int j = (1 << t) - 1 + (v & ((1 << t) - 1));
    sG[tid] = b * MPT + j;
    sP[tid] = b * MPT + ((j - 1) >> 1);
  }
  __syncthreads();

  // ---- stage A = [Xb | (htild/h_bu) | (h_td parent)] into swizzled LDS ----
#pragma unroll
  for (int it = 0; it < 4; ++it) {
    int idx = tid + it * 256, n = idx >> 4, e = idx & 15;
    st8(sA, n, RB, e, g8(Xb + (size_t)sG[n] * HS + e * 8));
  }
  if constexpr (MODE >= 1) {
#pragma unroll
    for (int it = 0; it < 4; ++it) {
      int idx = tid + it * 256, n = idx >> 4, e = idx & 15;
      st8(sA, n, RB, 16 + e, g8(h_bu + (size_t)sG[n] * HS + e * 8));
    }
  }
  if constexpr (MODE == 3) {
#pragma unroll
    for (int it = 0; it < 4; ++it) {
      int idx = tid + it * 256, n = idx >> 4, e = idx & 15;
      st8(sA, n, RB, 32 + e, g8(h_td + (size_t)sP[n] * HS + e * 8));
    }
  }
  __syncthreads();

  // ---- iou GEMM: 64 x 384, K = KA; register double-buffered A and B ----
  f32x4 acc[6][4];  // [g2*2+nf][mf]
#pragma unroll
  for (int p = 0; p < 6; ++p)
#pragma unroll
    for (int mf = 0; mf < 4; ++mf) acc[p][mf] = 0.0f;

  bf16x8 A0[4], A1[4], B0[6], B1[6];
  auto ldA = [&](int ks, bf16x8* Ad) {
#pragma unroll
    for (int mf = 0; mf < 4; ++mf) Ad[mf] = ld8(sA, mf * 16 + lr, RB, ks * 64 + lk * 16);
  };
  auto ldB = [&](int ks, bf16x8* Bd) {
#pragma unroll
    for (int g2 = 0; g2 < 3; ++g2)
#pragma unroll
      for (int nf = 0; nf < 2; ++nf)
        Bd[g2 * 2 + nf] = g8(W + (size_t)(g2 * 128 + w * 32 + nf * 16 + lr) * BK + ks * 32 + lk * 8);
  };
  auto domm = [&](bf16x8* Ad, bf16x8* Bd) {
#pragma unroll
    for (int p = 0; p < 6; ++p)
#pragma unroll
      for (int mf = 0; mf < 4; ++mf) acc[p][mf] = mm(Ad[mf], Bd[p], acc[p][mf]);
  };

  ldA(0, A0); ldB(0, B0);
#pragma unroll
  for (int ks2 = 0; ks2 < KS / 2; ++ks2) {
    ldA(2 * ks2 + 1, A1); ldB(2 * ks2 + 1, B1);
    domm(A0, B0);
    if (2 * ks2 + 2 < KS) { ldA(2 * ks2 + 2, A0); ldB(2 * ks2 + 2, B0); }
    domm(A1, B1);
  }

  // ---- batched prefetch: cbase + biases (+ Uf fragments for EPI) ----
  float cb[2][4][4];
  float bia[2], boa[2], bua[2], bfa[2];
#pragma unroll
  for (int nf = 0; nf < 2; ++nf) {
    const int ch = w * 32 + nf * 16 + lr;
    bia[nf] = bp[ch]; boa[nf] = bp[ch + 128]; bua[nf] = bp[ch + 256];
    if constexpr (EPI) bfa[nf] = bf_[ch];
    if constexpr (MODE == 1 || MODE == 3) {
#pragma unroll
      for (int mf = 0; mf < 4; ++mf)
#pragma unroll
        for (int j = 0; j < 4; ++j) {
          const int nrow = 16 * mf + lk * 4 + j;
          const int src = (MODE == 1) ? sG[nrow] : sP[nrow];
          cb[nf][mf][j] = cws[(size_t)src * HS + ch];
        }
    }
  }
  bf16x8 Uff[8];
  if constexpr (EPI) {
#pragma unroll
    for (int ks = 0; ks < 4; ++ks)
#pragma unroll
      for (int nf = 0; nf < 2; ++nf)
        Uff[ks * 2 + nf] = g8(Uf + (size_t)(w * 32 + nf * 16 + lr) * HS + ks * 32 + lk * 8);
  }

  // ---- gating ----
  __bf16* hp = (MODE == 3) ? h_td : h_bu;
  float cnv[2][4][4], hnv[2][4][4];
  float psum[2] = {0.0f, 0.0f};
#pragma unroll
  for (int nf = 0; nf < 2; ++nf) {
    const int ch = w * 32 + nf * 16 + lr;
#pragma unroll
    for (int mf = 0; mf < 4; ++mf)
#pragma unroll
      for (int j = 0; j < 4; ++j) {
        const int nrow = 16 * mf + lk * 4 + j;
        float cbase = (MODE == 0) ? 0.0f : cb[nf][mf][j];
        float cn = sigf(acc[nf][mf][j] + bia[nf]) * tanh_fast(acc[4 + nf][mf][j] + bua[nf]) + cbase;
        float hn = sigf(acc[2 + nf][mf][j] + boa[nf]) * tanh_fast(cn);
        if constexpr (!LEAFOUT) hp[(size_t)sG[nrow] * HS + ch] = (__bf16)hn;
        if constexpr (EPI) { cnv[nf][mf][j] = cn; hnv[nf][mf][j] = hn; }
        if constexpr (LEAFOUT) psum[nf] += hn;
      }
  }

  if constexpr (LEAFOUT) {   // block covers 64 leaves of one tree: reduce over lk
#pragma unroll
    for (int nf = 0; nf < 2; ++nf) {
      float s = psum[nf];
      s += __shfl_xor(s, 16);
      s += __shfl_xor(s, 32);
      if (lk == 0) part[(size_t)blockIdx.x * 128 + w * 32 + nf * 16 + lr] = s;
    }
  }

  // ---- epilogue: f = sig(Uf h + bf); push to parents (BU) / own row (TD) ----
  if constexpr (EPI) {
    __syncthreads();
#pragma unroll
    for (int nf = 0; nf < 2; ++nf) {
      const int ch = w * 32 + nf * 16 + lr;
#pragma unroll
      for (int mf = 0; mf < 4; ++mf)
#pragma unroll
        for (int j = 0; j < 4; ++j)
          stbf(sA, 16 * mf + lk * 4 + j, RB, HB + 2 * ch, hnv[nf][mf][j]);
    }
    __syncthreads();
    f32x4 fa[4][2];
#pragma unroll
    for (int mf = 0; mf < 4; ++mf) { fa[mf][0] = 0.0f; fa[mf][1] = 0.0f; }
#pragma unroll
    for (int ks = 0; ks < 4; ++ks) {
      bf16x8 a0 = ld8(sA, lr,      RB, HB + ks * 64 + lk * 16);
      bf16x8 a1 = ld8(sA, 16 + lr, RB, HB + ks * 64 + lk * 16);
      bf16x8 a2 = ld8(sA, 32 + lr, RB, HB + ks * 64 + lk * 16);
      bf16x8 a3 = ld8(sA, 48 + lr, RB, HB + ks * 64 + lk * 16);
#pragma unroll
      for (int nf = 0; nf < 2; ++nf) {
        fa[0][nf] = mm(a0, Uff[ks * 2 + nf], fa[0][nf]);
        fa[1][nf] = mm(a1, Uff[ks * 2 + nf], fa[1][nf]);
        fa[2][nf] = mm(a2, Uff[ks * 2 + nf], fa[2][nf]);
        fa[3][nf] = mm(a3, Uff[ks * 2 + nf], fa[3][nf]);
      }
    }
#pragma unroll
    for (int nf = 0; nf < 2; ++nf) {
      const int ch = w * 32 + nf * 16 + lr;
      if constexpr (MODE == 3) {
#pragma unroll
        for (int mf = 0; mf < 4; ++mf)
#pragma unroll
          for (int j = 0; j < 4; ++j) {
            const int nrow = 16 * mf + lk * 4 + j;
            cws[(size_t)sG[nrow] * HS + ch] = sigf(fa[mf][nf][j] + bfa[nf]) * cnv[nf][mf][j];
          }
      } else {
#pragma unroll
        for (int mf = 0; mf < 4; ++mf)
#pragma unroll
          for (int p = 0; p < 2; ++p) {
            const int er = 16 * mf + lk * 4 + 2 * p;
            float f0 = sigf(fa[mf][nf][2 * p]     + bfa[nf]) * cnv[nf][mf][2 * p];
            float f1 = sigf(fa[mf][nf][2 * p + 1] + bfa[nf]) * cnv[nf][mf][2 * p + 1];
            const int gp = sP[er];
            cws[(size_t)gp * HS + ch] = f0 + f1;
            h_bu[(size_t)gp * HS + ch] = (__bf16)(hnv[nf][mf][2 * p] + hnv[nf][mf][2 * p + 1]);
          }
      }
    }
  }
}

// ---------------------------------------------------------------------------
// BU small levels t=4..0, one block per tree; state (cred/htild) kept in LDS.
// ---------------------------------------------------------------------------
__global__ void __launch_bounds__(256)
bu_small(const __bf16* __restrict__ Xb, const __bf16* __restrict__ W,
         const float* __restrict__ bp, const __bf16* __restrict__ Uf,
         const float* __restrict__ bf_, __bf16* __restrict__ h_bu,
         const float* __restrict__ cws)
{
  __shared__ __align__(16) char sA[16 * 512];
  __shared__ float sCr[16][HS];
  __shared__ int sG[16];
  const int tid = threadIdx.x, w = tid >> 6, l = tid & 63, lr = l & 15, lk = l >> 4;
  const int b = blockIdx.x;
  const int n = tid >> 4, e = tid & 15;

  for (int t = 4; t >= 0; --t) {
    const int cnt = 1 << t, j0 = cnt - 1;
    if (tid < 16) { int r = tid < cnt ? tid : cnt - 1; sG[tid] = b * MPT + j0 + r; }
    __syncthreads();
    st8(sA, n, 512, e, g8(Xb + (size_t)sG[n] * HS + e * 8));
    if (t == 4) st8(sA, n, 512, 16 + e, g8(h_bu + (size_t)sG[n] * HS + e * 8));
    __syncthreads();

    f32x4 acc[3][2];
#pragma unroll
    for (int g2 = 0; g2 < 3; ++g2) { acc[g2][0] = 0.0f; acc[g2][1] = 0.0f; }
#pragma unroll
    for (int ks = 0; ks < 8; ++ks) {
      bf16x8 a0 = ld8(sA, lr, 512, ks * 64 + lk * 16);
#pragma unroll
      for (int g2 = 0; g2 < 3; ++g2)
#pragma unroll
        for (int nf = 0; nf < 2; ++nf) {
          bf16x8 bb = g8(W + (size_t)(g2 * 128 + w * 32 + nf * 16 + lr) * 256 + ks * 32 + lk * 8);
          acc[g2][nf] = mm(a0, bb, acc[g2][nf]);
        }
    }
    float cnv[2][4], hnv[2][4];
#pragma unroll
    for (int nf = 0; nf < 2; ++nf) {
      const int ch = w * 32 + nf * 16 + lr;
      const float bi = bp[ch], bo = bp[ch + 128], bu_ = bp[ch + 256];
#pragma unroll
      for (int j = 0; j < 4; ++j) {
        int r = lk * 4 + j;
        float cbv = (t == 4) ? cws[(size_t)sG[r] * HS + ch] : sCr[r][ch];
        float cn = sigf(acc[0][nf][j] + bi) * tanh_fast(acc[2][nf][j] + bu_) + cbv;
        float hn = sigf(acc[1][nf][j] + bo) * tanh_fast(cn);
        if (r < cnt) h_bu[(size_t)sG[r] * HS + ch] = (__bf16)hn;
        cnv[nf][j] = cn; hnv[nf][j] = hn;
      }
    }
    if (t > 0) {
      __syncthreads();
#pragma unroll
      for (int nf = 0; nf < 2; ++nf) {
        const int ch = w * 32 + nf * 16 + lr;
#pragma unroll
        for (int j = 0; j < 4; ++j) stbf(sA, lk * 4 + j, 512, 2 * ch, hnv[nf][j]);
      }
      __syncthreads();
      f32x4 fa[2]; fa[0] = 0.0f; fa[1] = 0.0f;
#pragma unroll
      for (int ks = 0; ks < 4; ++ks) {
        bf16x8 a0 = ld8(sA, lr, 512, ks * 64 + lk * 16);
#pragma unroll
        for (int nf = 0; nf < 2; ++nf) {
          bf16x8 bb = g8(Uf + (size_t)(w * 32 + nf * 16 + lr) * HS + ks * 32 + lk * 8);
          fa[nf] = mm(a0, bb, fa[nf]);
        }
      }
#pragma unroll
      for (int nf = 0; nf < 2; ++nf) {
        const int ch = w * 32 + nf * 16 + lr;
        const float bfv = bf_[ch];
#pragma unroll
        for (int p = 0; p < 2; ++p) {
          int pr = lk * 2 + p;
          if (pr < (cnt >> 1)) {
            float f0 = sigf(fa[nf][2 * p]     + bfv) * cnv[nf][2 * p];
            float f1 = sigf(fa[nf][2 * p + 1] + bfv) * cnv[nf][2 * p + 1];
            sCr[pr][ch] = f0 + f1;
            stbf(sA, pr, 512, 2 * (128 + ch), hnv[nf][2 * p] + hnv[nf][2 * p + 1]);
          }
        }
      }
      __syncthreads();
    }
  }
}

// ---------------------------------------------------------------------------
// TD small levels t=0..4, one block per tree; h/fc state in LDS.
// ---------------------------------------------------------------------------
__global__ void __launch_bounds__(256)
td_small(const __bf16* __restrict__ Xb, const __bf16* __restrict__ W,
         const float* __restrict__ bp, const __bf16* __restrict__ Uf,
         const float* __restrict__ bf_, const __bf16* __restrict__ h_bu,
         __bf16* __restrict__ h_td, float* __restrict__ cws)
{
  __shared__ __align__(16) char sA[16 * 768];
  __shared__ __align__(16) char sHt[16 * 256];
  __shared__ float sFc[16][HS];
  __shared__ int sG[16];
  const int tid = threadIdx.x, w = tid >> 6, l = tid & 63, lr = l & 15, lk = l >> 4;
  const int b = blockIdx.x;
  const int n = tid >> 4, e = tid & 15;

  for (int t = 0; t <= 4; ++t) {
    const int cnt = 1 << t, j0 = cnt - 1;
    if (tid < 16) { int r = tid < cnt ? tid : cnt - 1; sG[tid] = b * MPT + j0 + r; }
    __syncthreads();
    st8(sA, n, 768, e,      g8(Xb   + (size_t)sG[n] * HS + e * 8));
    st8(sA, n, 768, 16 + e, g8(h_bu + (size_t)sG[n] * HS + e * 8));
    if (t > 0) { bf16x8 v = ld8(sHt, n >> 1, 256, e * 16); st8(sA, n, 768, 32 + e, v); }
    __syncthreads();

    f32x4 acc[3][2];
#pragma unroll
    for (int g2 = 0; g2 < 3; ++g2) { acc[g2][0] = 0.0f; acc[g2][1] = 0.0f; }
    auto step = [&](int ks) {
      bf16x8 a0 = ld8(sA, lr, 768, ks * 64 + lk * 16);
#pragma unroll
      for (int g2 = 0; g2 < 3; ++g2)
#pragma unroll
        for (int nf = 0; nf < 2; ++nf) {
          bf16x8 bb = g8(W + (size_t)(g2 * 128 + w * 32 + nf * 16 + lr) * 384 + ks * 32 + lk * 8);
          acc[g2][nf] = mm(a0, bb, acc[g2][nf]);
        }
    };
#pragma unroll
    for (int ks = 0; ks < 8; ++ks) step(ks);
    if (t > 0) {
#pragma unroll
      for (int ks = 8; ks < 12; ++ks) step(ks);
    }

    float cnv[2][4], hnv[2][4];
#pragma unroll
    for (int nf = 0; nf < 2; ++nf) {
      const int ch = w * 32 + nf * 16 + lr;
      const float bi = bp[ch], bo = bp[ch + 128], bu_ = bp[ch + 256];
#pragma unroll
      for (int j = 0; j < 4; ++j) {
        int r = lk * 4 + j;
        float cbv = (t == 0) ? 0.0f : sFc[r >> 1][ch];
        float cn = sigf(acc[0][nf][j] + bi) * tanh_fast(acc[2][nf][j] + bu_) + cbv;
        float hn = sigf(acc[1][nf][j] + bo) * tanh_fast(cn);
        if (r < cnt) h_td[(size_t)sG[r] * HS + ch] = (__bf16)hn;
        cnv[nf][j] = cn; hnv[nf][j] = hn;
      }
    }
    __syncthreads();
#pragma unroll
    for (int nf = 0; nf < 2; ++nf) {
      const int ch = w * 32 + nf * 16 + lr;
#pragma unroll
      for (int j = 0; j < 4; ++j) stbf(sHt, lk * 4 + j, 256, 2 * ch, hnv[nf][j]);
    }
    __syncthreads();
    f32x4 fa[2]; fa[0] = 0.0f; fa[1] = 0.0f;
#pragma unroll
    for (int ks = 0; ks < 4; ++ks) {
      bf16x8 a0 = ld8(sHt, lr, 256, ks * 64 + lk * 16);
#pragma unroll
      for (int nf = 0; nf < 2; ++nf) {
        bf16x8 bb = g8(Uf + (size_t)(w * 32 + nf * 16 + lr) * HS + ks * 32 + lk * 8);
        fa[nf] = mm(a0, bb, fa[nf]);
      }
    }
#pragma unroll
    for (int nf = 0; nf < 2; ++nf) {
      const int ch = w * 32 + nf * 16 + lr;
      const float bfv = bf_[ch];
#pragma unroll
      for (int j = 0; j < 4; ++j) {
        int r = lk * 4 + j;
        float fc = sigf(fa[nf][j] + bfv) * cnv[nf][j];
        if (r < cnt) {
          if (t < 4) sFc[r][ch] = fc;
          else       cws[(size_t)sG[r] * HS + ch] = fc;
        }
      }
    }
    __syncthreads();
  }
}

// ---------------------------------------------------------------------------
__global__ void __launch_bounds__(256)
prep(const float* __restrict__ Wbu, const float* __restrict__ Ubu,
     const float* __restrict__ Wtd, const float* __restrict__ Utd,
     const float* __restrict__ Ufb, const float* __restrict__ Uft,
     __bf16* wbu, __bf16* wtd, __bf16* ufb, __bf16* uft)
{
  int i = blockIdx.x * 256 + threadIdx.x;
  if (i < 98304) {
    int r = i >> 8, c = i & 255;
    wbu[i] = (__bf16)(c < 128 ? Wbu[r * 128 + c] : Ubu[r * 128 + c - 128]);
  } else if (i < 245760) {
    int k = i - 98304; int r = k / 384, c = k - r * 384;
    wtd[k] = (__bf16)(c < 256 ? Wtd[r * 256 + c] : Utd[r * 128 + (c - 256)]);
  } else if (i < 262144) {
    int k = i - 245760; ufb[k] = (__bf16)Ufb[k];
  } else {
    int k = i - 262144; uft[k] = (__bf16)Uft[k];
  }
}

__global__ void __launch_bounds__(256)
cvtX_k(const float* __restrict__ X, __bf16* __restrict__ Xb)
{
  for (size_t idx = blockIdx.x * 256 + threadIdx.x; idx < (size_t)NNODE * 16;
       idx += (size_t)2048 * 256) {
    float4 v0 = reinterpret_cast<const float4*>(X)[idx * 2];
    float4 v1 = reinterpret_cast<const float4*>(X)[idx * 2 + 1];
    bf16x8 o;
    o[0] = (__bf16)v0.x; o[1] = (__bf16)v0.y; o[2] = (__bf16)v0.z; o[3] = (__bf16)v0.w;
    o[4] = (__bf16)v1.x; o[5] = (__bf16)v1.y; o[6] = (__bf16)v1.z; o[7] = (__bf16)v1.w;
    reinterpret_cast<bf16x8*>(Xb)[idx] = o;
  }
}

__global__ void __launch_bounds__(128)
finalize_kernel(const __bf16* __restrict__ h_bu, const float* __restrict__ part,
                float* __restrict__ out)
{
  int b = blockIdx.x, ch = threadIdx.x;
  out[(size_t)b * 256 + ch] = (float)h_bu[((size_t)b * MPT) * HS + ch];
  const float* pp = part + (size_t)b * 512 + ch;
  out[(size_t)b * 256 + 128 + ch] = (pp[0] + pp[128] + pp[256] + pp[384]) * (1.0f / 256.0f);
}

extern "C" void kernel_launch(void* const* d_in, const int* in_sizes, int n_in,
                              void* d_out, int out_size, void* d_ws, size_t ws_size,
                              hipStream_t stream) {
  const float* X     = (const float*)d_in[0];
  const float* W_bu  = (const float*)d_in[3];
  const float* U_bu  = (const float*)d_in[4];
  const float* b_bu  = (const float*)d_in[5];
  const float* Uf_bu = (const float*)d_in[6];
  const float* bf_bu = (const float*)d_in[7];
  const float* W_td  = (const float*)d_in[8];
  const float* U_td  = (const float*)d_in[9];
  const float* b_td  = (const float*)d_in[10];
  const float* Uf_td = (const float*)d_in[11];
  const float* bf_td = (const float*)d_in[12];

  char* p = (char*)d_ws;
  __bf16* wbu  = (__bf16*)p; p += (size_t)384 * 256 * 2;
  __bf16* wtd  = (__bf16*)p; p += (size_t)384 * 384 * 2;
  __bf16* ufb  = (__bf16*)p; p += (size_t)128 * 128 * 2;
  __bf16* uft  = (__bf16*)p; p += (size_t)128 * 128 * 2;
  __bf16* Xb   = (__bf16*)p; p += (size_t)NNODE * HS * 2;
  __bf16* h_bu = (__bf16*)p; p += (size_t)NNODE * HS * 2;
  __bf16* h_td = (__bf16*)p; p += (size_t)NNODE * HS * 2;
  float*  cws  = (float*)p;  p += (size_t)NNODE * HS * 4;
  float*  part = (float*)p;  // 1024 * 128 f32

  prep<<<1088, 256, 0, stream>>>(W_bu, U_bu, W_td, U_td, Uf_bu, Uf_td, wbu, wtd, ufb, uft);
  cvtX_k<<<2048, 256, 0, stream>>>(X, Xb);

  // bottom-up
  level_big<0, true><<<1024, 256, 0, stream>>>(8, Xb, wbu, b_bu, ufb, bf_bu, h_bu, h_td, cws, part);
  level_big<1, true><<<512,  256, 0, stream>>>(7, Xb, wbu, b_bu, ufb, bf_bu, h_bu, h_td, cws, part);
  level_big<1, true><<<256,  256, 0, stream>>>(6, Xb, wbu, b_bu, ufb, bf_bu, h_bu, h_td, cws, part);
  level_big<1, true><<<128,  256, 0, stream>>>(5, Xb, wbu, b_bu, ufb, bf_bu, h_bu, h_td, cws, part);
  bu_small<<<256, 256, 0, stream>>>(Xb, wbu, b_bu, ufb, bf_bu, h_bu, cws);

  // top-down
  td_small<<<256, 256, 0, stream>>>(Xb, wtd, b_td, uft, bf_td, h_bu, h_td, cws);
  level_big<3, true ><<<128,  256, 0, stream>>>(5, Xb, wtd, b_td, uft, bf_td, h_bu, h_td, cws, part);
  level_big<3, true ><<<256,  256, 0, stream>>>(6, Xb, wtd, b_td, uft, bf_td, h_bu, h_td, cws, part);
  level_big<3, true ><<<512,  256, 0, stream>>>(7, Xb, wtd, b_td, uft, bf_td, h_bu, h_td, cws, part);
  level_big<3, false><<<1024, 256, 0, stream>>>(8, Xb, wtd, b_td, uft, bf_td, h_bu, h_td, cws, part);

  finalize_kernel<<<256, 128, 0, stream>>>(h_bu, part, (float*)d_out);
}

// Round 5
// 375.597 us; speedup vs baseline: 6.3627x; 1.0556x over previous
//
#include <hip/hip_runtime.h>
#include <cmath>

#define NTREE 256
#define MPT 511
#define NNODE (NTREE * MPT)   // 130816
#define HS 128

typedef __bf16 bf16x8 __attribute__((ext_vector_type(8)));
typedef float  f32x4  __attribute__((ext_vector_type(4)));

__device__ __forceinline__ float sigf(float x) {
  float e = __builtin_amdgcn_exp2f(x * -1.44269504f);
  return __builtin_amdgcn_rcpf(1.0f + e);
}
__device__ __forceinline__ float tanh_fast(float x) {
  float e = __builtin_amdgcn_exp2f(x * -2.88539008f);
  return __builtin_amdgcn_rcpf(1.0f + e) * 2.0f - 1.0f;
}
__device__ __forceinline__ f32x4 mm(bf16x8 a, bf16x8 b, f32x4 c) {
  return __builtin_amdgcn_mfma_f32_16x16x32_bf16(a, b, c, 0, 0, 0);
}
// XOR-swizzled LDS tile helpers (T2): row-major bf16, 16B chunk swizzle
__device__ __forceinline__ int swz(int row, int rb, int kb) { return row * rb + (kb ^ ((row & 7) << 4)); }
__device__ __forceinline__ void st8(char* s, int row, int rb, int chunk, bf16x8 v) {
  *reinterpret_cast<bf16x8*>(s + swz(row, rb, chunk * 16)) = v;
}
__device__ __forceinline__ bf16x8 ld8(const char* s, int row, int rb, int kb) {
  return *reinterpret_cast<const bf16x8*>(s + swz(row, rb, kb));
}
__device__ __forceinline__ bf16x8 g8(const __bf16* p) { return *reinterpret_cast<const bf16x8*>(p); }
__device__ __forceinline__ void stbf(char* s, int row, int rb, int kbyte, float v) {
  *reinterpret_cast<__bf16*>(s + row * rb + (kbyte ^ ((row & 7) << 4))) = (__bf16)v;
}

// ---------------------------------------------------------------------------
// Big-level kernel (unchanged from round 4): 64 nodes/block, 4 waves.
// MODE: 0 = BU leaf (K=128), 1 = BU internal (K=256), 3 = TD (K=384)
// ---------------------------------------------------------------------------
template <int MODE, bool EPI>
__global__ void __launch_bounds__(256, 2)
level_big(int t,
          const __bf16* __restrict__ Xb,
          const __bf16* __restrict__ W,
          const float*  __restrict__ bp,
          const __bf16* __restrict__ Uf,
          const float*  __restrict__ bf_,
          __bf16* __restrict__ h_bu,
          __bf16* __restrict__ h_td,
          float*  __restrict__ cws,
          float*  __restrict__ part)
{
  constexpr int KA = (MODE == 0) ? 128 : (MODE == 1) ? 256 : 384;
  constexpr int KS = KA / 32;
  constexpr int BK = (MODE == 3) ? 384 : 256;
  constexpr int RB = KA * 2;
  constexpr int HB = (MODE == 0) ? 0 : (MODE == 1) ? 256 : 512;
  constexpr bool LEAFOUT = (MODE == 3 && !EPI);

  __shared__ __align__(16) char sA[64 * RB];
  __shared__ int sG[64], sP[64];

  const int tid = threadIdx.x;
  const int w = tid >> 6, l = tid & 63, lr = l & 15, lk = l >> 4;

  if (tid < 64) {
    int v = blockIdx.x * 64 + tid;
    int b = v >> t;
    int j = (1 << t) - 1 + (v & ((1 << t) - 1));
    sG[tid] = b * MPT + j;
    sP[tid] = b * MPT + ((j - 1) >> 1);
  }
  __syncthreads();

#pragma unroll
  for (int it = 0; it < 4; ++it) {
    int idx = tid + it * 256, n = idx >> 4, e = idx & 15;
    st8(sA, n, RB, e, g8(Xb + (size_t)sG[n] * HS + e * 8));
  }
  if constexpr (MODE >= 1) {
#pragma unroll
    for (int it = 0; it < 4; ++it) {
      int idx = tid + it * 256, n = idx >> 4, e = idx & 15;
      st8(sA, n, RB, 16 + e, g8(h_bu + (size_t)sG[n] * HS + e * 8));
    }
  }
  if constexpr (MODE == 3) {
#pragma unroll
    for (int it = 0; it < 4; ++it) {
      int idx = tid + it * 256, n = idx >> 4, e = idx & 15;
      st8(sA, n, RB, 32 + e, g8(h_td + (size_t)sP[n] * HS + e * 8));
    }
  }
  __syncthreads();

  f32x4 acc[6][4];
#pragma unroll
  for (int p = 0; p < 6; ++p)
#pragma unroll
    for (int mf = 0; mf < 4; ++mf) acc[p][mf] = 0.0f;

  bf16x8 A0[4], A1[4], B0[6], B1[6];
  auto ldA = [&](int ks, bf16x8* Ad) {
#pragma unroll
    for (int mf = 0; mf < 4; ++mf) Ad[mf] = ld8(sA, mf * 16 + lr, RB, ks * 64 + lk * 16);
  };
  auto ldB = [&](int ks, bf16x8* Bd) {
#pragma unroll
    for (int g2 = 0; g2 < 3; ++g2)
#pragma unroll
      for (int nf = 0; nf < 2; ++nf)
        Bd[g2 * 2 + nf] = g8(W + (size_t)(g2 * 128 + w * 32 + nf * 16 + lr) * BK + ks * 32 + lk * 8);
  };
  auto domm = [&](bf16x8* Ad, bf16x8* Bd) {
#pragma unroll
    for (int p = 0; p < 6; ++p)
#pragma unroll
      for (int mf = 0; mf < 4; ++mf) acc[p][mf] = mm(Ad[mf], Bd[p], acc[p][mf]);
  };

  ldA(0, A0); ldB(0, B0);
#pragma unroll
  for (int ks2 = 0; ks2 < KS / 2; ++ks2) {
    ldA(2 * ks2 + 1, A1); ldB(2 * ks2 + 1, B1);
    domm(A0, B0);
    if (2 * ks2 + 2 < KS) { ldA(2 * ks2 + 2, A0); ldB(2 * ks2 + 2, B0); }
    domm(A1, B1);
  }

  float cb[2][4][4];
  float bia[2], boa[2], bua[2], bfa[2];
#pragma unroll
  for (int nf = 0; nf < 2; ++nf) {
    const int ch = w * 32 + nf * 16 + lr;
    bia[nf] = bp[ch]; boa[nf] = bp[ch + 128]; bua[nf] = bp[ch + 256];
    if constexpr (EPI) bfa[nf] = bf_[ch];
    if constexpr (MODE == 1 || MODE == 3) {
#pragma unroll
      for (int mf = 0; mf < 4; ++mf)
#pragma unroll
        for (int j = 0; j < 4; ++j) {
          const int nrow = 16 * mf + lk * 4 + j;
          const int src = (MODE == 1) ? sG[nrow] : sP[nrow];
          cb[nf][mf][j] = cws[(size_t)src * HS + ch];
        }
    }
  }
  bf16x8 Uff[8];
  if constexpr (EPI) {
#pragma unroll
    for (int ks = 0; ks < 4; ++ks)
#pragma unroll
      for (int nf = 0; nf < 2; ++nf)
        Uff[ks * 2 + nf] = g8(Uf + (size_t)(w * 32 + nf * 16 + lr) * HS + ks * 32 + lk * 8);
  }

  __bf16* hp = (MODE == 3) ? h_td : h_bu;
  float cnv[2][4][4], hnv[2][4][4];
  float psum[2] = {0.0f, 0.0f};
#pragma unroll
  for (int nf = 0; nf < 2; ++nf) {
    const int ch = w * 32 + nf * 16 + lr;
#pragma unroll
    for (int mf = 0; mf < 4; ++mf)
#pragma unroll
      for (int j = 0; j < 4; ++j) {
        const int nrow = 16 * mf + lk * 4 + j;
        float cbase = (MODE == 0) ? 0.0f : cb[nf][mf][j];
        float cn = sigf(acc[nf][mf][j] + bia[nf]) * tanh_fast(acc[4 + nf][mf][j] + bua[nf]) + cbase;
        float hn = sigf(acc[2 + nf][mf][j] + boa[nf]) * tanh_fast(cn);
        if constexpr (!LEAFOUT) hp[(size_t)sG[nrow] * HS + ch] = (__bf16)hn;
        if constexpr (EPI) { cnv[nf][mf][j] = cn; hnv[nf][mf][j] = hn; }
        if constexpr (LEAFOUT) psum[nf] += hn;
      }
  }

  if constexpr (LEAFOUT) {
#pragma unroll
    for (int nf = 0; nf < 2; ++nf) {
      float s = psum[nf];
      s += __shfl_xor(s, 16);
      s += __shfl_xor(s, 32);
      if (lk == 0) part[(size_t)blockIdx.x * 128 + w * 32 + nf * 16 + lr] = s;
    }
  }

  if constexpr (EPI) {
    __syncthreads();
#pragma unroll
    for (int nf = 0; nf < 2; ++nf) {
      const int ch = w * 32 + nf * 16 + lr;
#pragma unroll
      for (int mf = 0; mf < 4; ++mf)
#pragma unroll
        for (int j = 0; j < 4; ++j)
          stbf(sA, 16 * mf + lk * 4 + j, RB, HB + 2 * ch, hnv[nf][mf][j]);
    }
    __syncthreads();
    f32x4 fa[4][2];
#pragma unroll
    for (int mf = 0; mf < 4; ++mf) { fa[mf][0] = 0.0f; fa[mf][1] = 0.0f; }
#pragma unroll
    for (int ks = 0; ks < 4; ++ks) {
      bf16x8 a0 = ld8(sA, lr,      RB, HB + ks * 64 + lk * 16);
      bf16x8 a1 = ld8(sA, 16 + lr, RB, HB + ks * 64 + lk * 16);
      bf16x8 a2 = ld8(sA, 32 + lr, RB, HB + ks * 64 + lk * 16);
      bf16x8 a3 = ld8(sA, 48 + lr, RB, HB + ks * 64 + lk * 16);
#pragma unroll
      for (int nf = 0; nf < 2; ++nf) {
        fa[0][nf] = mm(a0, Uff[ks * 2 + nf], fa[0][nf]);
        fa[1][nf] = mm(a1, Uff[ks * 2 + nf], fa[1][nf]);
        fa[2][nf] = mm(a2, Uff[ks * 2 + nf], fa[2][nf]);
        fa[3][nf] = mm(a3, Uff[ks * 2 + nf], fa[3][nf]);
      }
    }
#pragma unroll
    for (int nf = 0; nf < 2; ++nf) {
      const int ch = w * 32 + nf * 16 + lr;
      if constexpr (MODE == 3) {
#pragma unroll
        for (int mf = 0; mf < 4; ++mf)
#pragma unroll
          for (int j = 0; j < 4; ++j) {
            const int nrow = 16 * mf + lk * 4 + j;
            cws[(size_t)sG[nrow] * HS + ch] = sigf(fa[mf][nf][j] + bfa[nf]) * cnv[nf][mf][j];
          }
      } else {
#pragma unroll
        for (int mf = 0; mf < 4; ++mf)
#pragma unroll
          for (int p = 0; p < 2; ++p) {
            const int er = 16 * mf + lk * 4 + 2 * p;
            float f0 = sigf(fa[mf][nf][2 * p]     + bfa[nf]) * cnv[nf][mf][2 * p];
            float f1 = sigf(fa[mf][nf][2 * p + 1] + bfa[nf]) * cnv[nf][mf][2 * p + 1];
            const int gp = sP[er];
            cws[(size_t)gp * HS + ch] = f0 + f1;
            h_bu[(size_t)gp * HS + ch] = (__bf16)(hnv[nf][mf][2 * p] + hnv[nf][mf][2 * p + 1]);
          }
      }
    }
  }
}

// ---------------------------------------------------------------------------
// Merged small-levels kernel: one block per tree. BU t=4..0 then TD t=0..4.
// All state LDS-resident: X rows j<31 (sX), true h_bu (sH), htild (sT, BU) /
// f-bounce (sT, TD), h_td j<15 (sTd), cred (sCr), fc (sFc).
// Global I/O: prefetch X + t=4 htild/cred; write root h_bu, t=4 h_td + fc.
// ---------------------------------------------------------------------------
__global__ void __launch_bounds__(256, 1)
small_both(const __bf16* __restrict__ Xb,
           const __bf16* __restrict__ Wbu, const float* __restrict__ bbu,
           const __bf16* __restrict__ Ufb, const float* __restrict__ bfb,
           const __bf16* __restrict__ Wtd, const float* __restrict__ btd,
           const __bf16* __restrict__ Uft, const float* __restrict__ bft,
           __bf16* __restrict__ h_bu, __bf16* __restrict__ h_td,
           float* __restrict__ cws)
{
  __shared__ __align__(16) char sX[31 * 256];
  __shared__ __align__(16) char sH[31 * 256];
  __shared__ __align__(16) char sT[16 * 256];
  __shared__ __align__(16) char sTd[15 * 256];
  __shared__ float sCr[16][128];
  __shared__ float sFc[16][128];

  const int tid = threadIdx.x, w = tid >> 6, l = tid & 63, lr = l & 15, lk = l >> 4;
  const size_t base = (size_t)blockIdx.x * MPT * HS;

  // ---- one-time prefetch ----
  for (int idx = tid; idx < 31 * 16; idx += 256) {
    int n = idx >> 4, e = idx & 15;
    st8(sX, n, 256, e, g8(Xb + base + (size_t)n * HS + e * 8));
  }
  { int n = tid >> 4, e = tid & 15;                       // htild t=4 (from big t=5 epi)
    st8(sT, n, 256, e, g8(h_bu + base + (size_t)(15 + n) * HS + e * 8)); }
  for (int idx = tid; idx < 16 * 32; idx += 256) {        // cred t=4
    int n = idx >> 5, e = idx & 31;
    reinterpret_cast<float4*>(&sCr[n][0])[e] =
        reinterpret_cast<const float4*>(cws + base + (size_t)(15 + n) * HS)[e];
  }
  for (int idx = tid; idx < 15 * 16; idx += 256)          // zero h_td state (root level)
    *reinterpret_cast<float4*>(sTd + idx * 16) = float4{0.f, 0.f, 0.f, 0.f};
  __syncthreads();

  // =================== BU phase: t = 4..0 ===================
  {
    float bia[2], boa[2], bua[2], bfa[2];
    bf16x8 Uff[8];
#pragma unroll
    for (int nf = 0; nf < 2; ++nf) {
      const int ch = w * 32 + nf * 16 + lr;
      bia[nf] = bbu[ch]; boa[nf] = bbu[ch + 128]; bua[nf] = bbu[ch + 256]; bfa[nf] = bfb[ch];
    }
#pragma unroll
    for (int ks = 0; ks < 4; ++ks)
#pragma unroll
      for (int nf = 0; nf < 2; ++nf)
        Uff[ks * 2 + nf] = g8(Ufb + (size_t)(w * 32 + nf * 16 + lr) * HS + ks * 32 + lk * 8);

    for (int t = 4; t >= 0; --t) {
      const int cnt = 1 << t, j0 = cnt - 1;
      f32x4 acc[6];
#pragma unroll
      for (int p = 0; p < 6; ++p) acc[p] = 0.0f;
      bf16x8 Bb[3][6], Aa[3];
      auto ldB = [&](int ks, int s) {
#pragma unroll
        for (int g2 = 0; g2 < 3; ++g2)
#pragma unroll
          for (int nf = 0; nf < 2; ++nf)
            Bb[s][g2 * 2 + nf] =
                g8(Wbu + (size_t)(g2 * 128 + w * 32 + nf * 16 + lr) * 256 + ks * 32 + lk * 8);
      };
      auto ldA = [&](int ks, int s) {
        const int kb = (ks & 3) * 64 + lk * 16;
        Aa[s] = (ks < 4) ? ld8(sX, j0 + lr, 256, kb) : ld8(sT, lr, 256, kb);
      };
      ldB(0, 0); ldA(0, 0); ldB(1, 1); ldA(1, 1);
#pragma unroll
      for (int ks = 0; ks < 8; ++ks) {
        if (ks + 2 < 8) { ldB(ks + 2, (ks + 2) % 3); ldA(ks + 2, (ks + 2) % 3); }
#pragma unroll
        for (int p = 0; p < 6; ++p) acc[p] = mm(Aa[ks % 3], Bb[ks % 3][p], acc[p]);
      }
      float cnv[2][4], hnv[2][4];
#pragma unroll
      for (int nf = 0; nf < 2; ++nf) {
        const int ch = w * 32 + nf * 16 + lr;
#pragma unroll
        for (int j = 0; j < 4; ++j) {
          const int r = lk * 4 + j;
          float cn = sigf(acc[nf][j] + bia[nf]) * tanh_fast(acc[4 + nf][j] + bua[nf]) + sCr[r][ch];
          float hn = sigf(acc[2 + nf][j] + boa[nf]) * tanh_fast(cn);
          cnv[nf][j] = cn; hnv[nf][j] = hn;
          if (r < cnt) stbf(sH, j0 + r, 256, 2 * ch, hn);
        }
      }
      if (t == 0 && lk == 0) {
#pragma unroll
        for (int nf = 0; nf < 2; ++nf)
          h_bu[base + w * 32 + nf * 16 + lr] = (__bf16)hnv[nf][0];   // root h_bu -> out
      }
      __syncthreads();
      if (t > 0) {
        f32x4 fa[2]; fa[0] = 0.0f; fa[1] = 0.0f;
#pragma unroll
        for (int ks = 0; ks < 4; ++ks) {
          bf16x8 a = ld8(sH, j0 + lr, 256, ks * 64 + lk * 16);
          fa[0] = mm(a, Uff[ks * 2 + 0], fa[0]);
          fa[1] = mm(a, Uff[ks * 2 + 1], fa[1]);
        }
#pragma unroll
        for (int nf = 0; nf < 2; ++nf) {
          const int ch = w * 32 + nf * 16 + lr;
#pragma unroll
          for (int p = 0; p < 2; ++p) {
            const int pr = lk * 2 + p;
            if (pr < (cnt >> 1)) {
              float f0 = sigf(fa[nf][2 * p]     + bfa[nf]) * cnv[nf][2 * p];
              float f1 = sigf(fa[nf][2 * p + 1] + bfa[nf]) * cnv[nf][2 * p + 1];
              sCr[pr][ch] = f0 + f1;
              stbf(sT, pr, 256, 2 * ch, hnv[nf][2 * p] + hnv[nf][2 * p + 1]);
            }
          }
        }
      }
      __syncthreads();
    }
  }

  // =================== TD phase: t = 0..4 ===================
  {
    float bia[2], boa[2], bua[2], bfa[2];
    bf16x8 Uff[8];
#pragma unroll
    for (int nf = 0; nf < 2; ++nf) {
      const int ch = w * 32 + nf * 16 + lr;
      bia[nf] = btd[ch]; boa[nf] = btd[ch + 128]; bua[nf] = btd[ch + 256]; bfa[nf] = bft[ch];
    }
#pragma unroll
    for (int ks = 0; ks < 4; ++ks)
#pragma unroll
      for (int nf = 0; nf < 2; ++nf)
        Uff[ks * 2 + nf] = g8(Uft + (size_t)(w * 32 + nf * 16 + lr) * HS + ks * 32 + lk * 8);

    for (int t = 0; t <= 4; ++t) {
      const int cnt = 1 << t, j0 = cnt - 1;
      f32x4 acc[6];
#pragma unroll
      for (int p = 0; p < 6; ++p) acc[p] = 0.0f;
      bf16x8 Bb[3][6], Aa[3];
      auto ldB = [&](int ks, int s) {
#pragma unroll
        for (int g2 = 0; g2 < 3; ++g2)
#pragma unroll
          for (int nf = 0; nf < 2; ++nf)
            Bb[s][g2 * 2 + nf] =
                g8(Wtd + (size_t)(g2 * 128 + w * 32 + nf * 16 + lr) * 384 + ks * 32 + lk * 8);
      };
      auto ldA = [&](int ks, int s) {
        const int kb = (ks & 3) * 64 + lk * 16;
        if (ks < 4)      Aa[s] = ld8(sX, j0 + lr, 256, kb);
        else if (ks < 8) Aa[s] = ld8(sH, j0 + lr, 256, kb);
        else { int pr = (j0 + lr - 1) >> 1; pr = pr < 0 ? 0 : pr;
               Aa[s] = ld8(sTd, pr, 256, kb); }
      };
      ldB(0, 0); ldA(0, 0); ldB(1, 1); ldA(1, 1);
#pragma unroll
      for (int ks = 0; ks < 12; ++ks) {
        if (ks + 2 < 12) { ldB(ks + 2, (ks + 2) % 3); ldA(ks + 2, (ks + 2) % 3); }
#pragma unroll
        for (int p = 0; p < 6; ++p) acc[p] = mm(Aa[ks % 3], Bb[ks % 3][p], acc[p]);
      }
      float cnv[2][4], hnv[2][4];
#pragma unroll
      for (int nf = 0; nf < 2; ++nf) {
        const int ch = w * 32 + nf * 16 + lr;
#pragma unroll
        for (int j = 0; j < 4; ++j) {
          const int r = lk * 4 + j;
          float cb = (t == 0) ? 0.0f : sFc[r >> 1][ch];
          float cn = sigf(acc[nf][j] + bia[nf]) * tanh_fast(acc[4 + nf][j] + bua[nf]) + cb;
          float hn = sigf(acc[2 + nf][j] + boa[nf]) * tanh_fast(cn);
          cnv[nf][j] = cn; hnv[nf][j] = hn;
          stbf(sT, r, 256, 2 * ch, hn);                       // f-GEMM bounce
          if (r < cnt && j0 + r < 15) stbf(sTd, j0 + r, 256, 2 * ch, hn);
          if (t == 4) h_td[base + (size_t)(15 + r) * HS + ch] = (__bf16)hn;
        }
      }
      __syncthreads();
      f32x4 fa[2]; fa[0] = 0.0f; fa[1] = 0.0f;
#pragma unroll
      for (int ks = 0; ks < 4; ++ks) {
        bf16x8 a = ld8(sT, lr, 256, ks * 64 + lk * 16);
        fa[0] = mm(a, Uff[ks * 2 + 0], fa[0]);
        fa[1] = mm(a, Uff[ks * 2 + 1], fa[1]);
      }
#pragma unroll
      for (int nf = 0; nf < 2; ++nf) {
        const int ch = w * 32 + nf * 16 + lr;
#pragma unroll
        for (int j = 0; j < 4; ++j) {
          const int r = lk * 4 + j;
          float fcv = sigf(fa[nf][j] + bfa[nf]) * cnv[nf][j];
          if (r < cnt) {
            if (t < 4) sFc[r][ch] = fcv;
            else       cws[base + (size_t)(15 + r) * HS + ch] = fcv;
          }
        }
      }
      __syncthreads();
    }
  }
}

// ---------------------------------------------------------------------------
__global__ void __launch_bounds__(256)
prep(const float* __restrict__ Wbu, const float* __restrict__ Ubu,
     const float* __restrict__ Wtd, const float* __restrict__ Utd,
     const float* __restrict__ Ufb, const float* __restrict__ Uft,
     __bf16* wbu, __bf16* wtd, __bf16* ufb, __bf16* uft)
{
  int i = blockIdx.x * 256 + threadIdx.x;
  if (i < 98304) {
    int r = i >> 8, c = i & 255;
    wbu[i] = (__bf16)(c < 128 ? Wbu[r * 128 + c] : Ubu[r * 128 + c - 128]);
  } else if (i < 245760) {
    int k = i - 98304; int r = k / 384, c = k - r * 384;
    wtd[k] = (__bf16)(c < 256 ? Wtd[r * 256 + c] : Utd[r * 128 + (c - 256)]);
  } else if (i < 262144) {
    int k = i - 245760; ufb[k] = (__bf16)Ufb[k];
  } else {
    int k = i - 262144; uft[k] = (__bf16)Uft[k];
  }
}

__global__ void __launch_bounds__(256)
cvtX_k(const float* __restrict__ X, __bf16* __restrict__ Xb)
{
  for (size_t idx = blockIdx.x * 256 + threadIdx.x; idx < (size_t)NNODE * 16;
       idx += (size_t)2048 * 256) {
    float4 v0 = reinterpret_cast<const float4*>(X)[idx * 2];
    float4 v1 = reinterpret_cast<const float4*>(X)[idx * 2 + 1];
    bf16x8 o;
    o[0] = (__bf16)v0.x; o[1] = (__bf16)v0.y; o[2] = (__bf16)v0.z; o[3] = (__bf16)v0.w;
    o[4] = (__bf16)v1.x; o[5] = (__bf16)v1.y; o[6] = (__bf16)v1.z; o[7] = (__bf16)v1.w;
    reinterpret_cast<bf16x8*>(Xb)[idx] = o;
  }
}

__global__ void __launch_bounds__(128)
finalize_kernel(const __bf16* __restrict__ h_bu, const float* __restrict__ part,
                float* __restrict__ out)
{
  int b = blockIdx.x, ch = threadIdx.x;
  out[(size_t)b * 256 + ch] = (float)h_bu[((size_t)b * MPT) * HS + ch];
  const float* pp = part + (size_t)b * 512 + ch;
  out[(size_t)b * 256 + 128 + ch] = (pp[0] + pp[128] + pp[256] + pp[384]) * (1.0f / 256.0f);
}

extern "C" void kernel_launch(void* const* d_in, const int* in_sizes, int n_in,
                              void* d_out, int out_size, void* d_ws, size_t ws_size,
                              hipStream_t stream) {
  const float* X     = (const float*)d_in[0];
  const float* W_bu  = (const float*)d_in[3];
  const float* U_bu  = (const float*)d_in[4];
  const float* b_bu  = (const float*)d_in[5];
  const float* Uf_bu = (const float*)d_in[6];
  const float* bf_bu = (const float*)d_in[7];
  const float* W_td  = (const float*)d_in[8];
  const float* U_td  = (const float*)d_in[9];
  const float* b_td  = (const float*)d_in[10];
  const float* Uf_td = (const float*)d_in[11];
  const float* bf_td = (const float*)d_in[12];

  char* p = (char*)d_ws;
  __bf16* wbu  = (__bf16*)p; p += (size_t)384 * 256 * 2;
  __bf16* wtd  = (__bf16*)p; p += (size_t)384 * 384 * 2;
  __bf16* ufb  = (__bf16*)p; p += (size_t)128 * 128 * 2;
  __bf16* uft  = (__bf16*)p; p += (size_t)128 * 128 * 2;
  __bf16* Xb   = (__bf16*)p; p += (size_t)NNODE * HS * 2;
  __bf16* h_bu = (__bf16*)p; p += (size_t)NNODE * HS * 2;
  __bf16* h_td = (__bf16*)p; p += (size_t)NNODE * HS * 2;
  float*  cws  = (float*)p;  p += (size_t)NNODE * HS * 4;
  float*  part = (float*)p;  // 1024 * 128 f32

  prep<<<1088, 256, 0, stream>>>(W_bu, U_bu, W_td, U_td, Uf_bu, Uf_td, wbu, wtd, ufb, uft);
  cvtX_k<<<2048, 256, 0, stream>>>(X, Xb);

  // bottom-up big levels t=8..5
  level_big<0, true><<<1024, 256, 0, stream>>>(8, Xb, wbu, b_bu, ufb, bf_bu, h_bu, h_td, cws, part);
  level_big<1, true><<<512,  256, 0, stream>>>(7, Xb, wbu, b_bu, ufb, bf_bu, h_bu, h_td, cws, part);
  level_big<1, true><<<256,  256, 0, stream>>>(6, Xb, wbu, b_bu, ufb, bf_bu, h_bu, h_td, cws, part);
  level_big<1, true><<<128,  256, 0, stream>>>(5, Xb, wbu, b_bu, ufb, bf_bu, h_bu, h_td, cws, part);

  // merged small levels: BU t=4..0 + TD t=0..4
  small_both<<<256, 256, 0, stream>>>(Xb, wbu, b_bu, ufb, bf_bu,
                                      wtd, b_td, uft, bf_td, h_bu, h_td, cws);

  // top-down big levels t=5..8
  level_big<3, true ><<<128,  256, 0, stream>>>(5, Xb, wtd, b_td, uft, bf_td, h_bu, h_td, cws, part);
  level_big<3, true ><<<256,  256, 0, stream>>>(6, Xb, wtd, b_td, uft, bf_td, h_bu, h_td, cws, part);
  level_big<3, true ><<<512,  256, 0, stream>>>(7, Xb, wtd, b_td, uft, bf_td, h_bu, h_td, cws, part);
  level_big<3, false><<<1024, 256, 0, stream>>>(8, Xb, wtd, b_td, uft, bf_td, h_bu, h_td, cws, part);

  finalize_kernel<<<256, 128, 0, stream>>>(h_bu, part, (float*)d_out);
}

// Round 6
// 337.222 us; speedup vs baseline: 7.0867x; 1.1138x over previous
//
#include <hip/hip_runtime.h>
#include <cmath>

#define NTREE 256
#define MPT 511
#define NNODE (NTREE * MPT)   // 130816
#define HS 128

typedef __bf16 bf16x8 __attribute__((ext_vector_type(8)));
typedef float  f32x4  __attribute__((ext_vector_type(4)));

__device__ __forceinline__ float sigf(float x) {
  float e = __builtin_amdgcn_exp2f(x * -1.44269504f);
  return __builtin_amdgcn_rcpf(1.0f + e);
}
__device__ __forceinline__ float tanh_fast(float x) {
  float e = __builtin_amdgcn_exp2f(x * -2.88539008f);
  return __builtin_amdgcn_rcpf(1.0f + e) * 2.0f - 1.0f;
}
__device__ __forceinline__ f32x4 mm(bf16x8 a, bf16x8 b, f32x4 c) {
  return __builtin_amdgcn_mfma_f32_16x16x32_bf16(a, b, c, 0, 0, 0);
}
// XOR-swizzled LDS tile helpers (T2): row-major bf16, 16B chunk swizzle
__device__ __forceinline__ int swz(int row, int rb, int kb) { return row * rb + (kb ^ ((row & 7) << 4)); }
__device__ __forceinline__ void st8(char* s, int row, int rb, int chunk, bf16x8 v) {
  *reinterpret_cast<bf16x8*>(s + swz(row, rb, chunk * 16)) = v;
}
__device__ __forceinline__ bf16x8 ld8(const char* s, int row, int rb, int kb) {
  return *reinterpret_cast<const bf16x8*>(s + swz(row, rb, kb));
}
__device__ __forceinline__ bf16x8 g8(const __bf16* p) { return *reinterpret_cast<const bf16x8*>(p); }
__device__ __forceinline__ bf16x8 gx8(const float* p) {   // f32 row -> bf16x8
  float4 v0 = reinterpret_cast<const float4*>(p)[0];
  float4 v1 = reinterpret_cast<const float4*>(p)[1];
  bf16x8 o;
  o[0] = (__bf16)v0.x; o[1] = (__bf16)v0.y; o[2] = (__bf16)v0.z; o[3] = (__bf16)v0.w;
  o[4] = (__bf16)v1.x; o[5] = (__bf16)v1.y; o[6] = (__bf16)v1.z; o[7] = (__bf16)v1.w;
  return o;
}
__device__ __forceinline__ void stbf(char* s, int row, int rb, int kbyte, float v) {
  *reinterpret_cast<__bf16*>(s + row * rb + (kbyte ^ ((row & 7) << 4))) = (__bf16)v;
}

// ---------------------------------------------------------------------------
// Big-level kernel: 64 nodes/block, 4 waves.
// MODE: 0 = BU leaf (K=128), 1 = BU internal (K=256), 3 = TD (K=384)
// ---------------------------------------------------------------------------
template <int MODE, bool EPI>
__global__ void __launch_bounds__(256, 2)
level_big(int t,
          const float*  __restrict__ Xf,
          const __bf16* __restrict__ W,
          const float*  __restrict__ bp,
          const __bf16* __restrict__ Uf,
          const float*  __restrict__ bf_,
          __bf16* __restrict__ h_bu,
          __bf16* __restrict__ h_td,
          float*  __restrict__ cws,
          float*  __restrict__ part)
{
  constexpr int KA = (MODE == 0) ? 128 : (MODE == 1) ? 256 : 384;
  constexpr int KS = KA / 32;
  constexpr int BK = (MODE == 3) ? 384 : 256;
  constexpr int RB = KA * 2;
  constexpr int HB = (MODE == 0) ? 0 : (MODE == 1) ? 256 : 512;
  constexpr bool LEAFOUT = (MODE == 3 && !EPI);

  __shared__ __align__(16) char sA[64 * RB];
  __shared__ int sG[64], sP[64];

  const int tid = threadIdx.x;
  const int w = tid >> 6, l = tid & 63, lr = l & 15, lk = l >> 4;

  if (tid < 64) {
    int v = blockIdx.x * 64 + tid;
    int b = v >> t;
    int j = (1 << t) - 1 + (v & ((1 << t) - 1));
    sG[tid] = b * MPT + j;
    sP[tid] = b * MPT + ((j - 1) >> 1);
  }
  __syncthreads();

#pragma unroll
  for (int it = 0; it < 4; ++it) {
    int idx = tid + it * 256, n = idx >> 4, e = idx & 15;
    st8(sA, n, RB, e, gx8(Xf + (size_t)sG[n] * HS + e * 8));
  }
  if constexpr (MODE >= 1) {
#pragma unroll
    for (int it = 0; it < 4; ++it) {
      int idx = tid + it * 256, n = idx >> 4, e = idx & 15;
      st8(sA, n, RB, 16 + e, g8(h_bu + (size_t)sG[n] * HS + e * 8));
    }
  }
  if constexpr (MODE == 3) {
#pragma unroll
    for (int it = 0; it < 4; ++it) {
      int idx = tid + it * 256, n = idx >> 4, e = idx & 15;
      st8(sA, n, RB, 32 + e, g8(h_td + (size_t)sP[n] * HS + e * 8));
    }
  }
  __syncthreads();

  // ---- iou GEMM: A 2-buffer (LDS), B 3-buffer (global, 2-step lookahead) ----
  f32x4 acc[6][4];
#pragma unroll
  for (int p = 0; p < 6; ++p)
#pragma unroll
    for (int mf = 0; mf < 4; ++mf) acc[p][mf] = 0.0f;

  bf16x8 A0[4], A1[4], Bb[3][6];
  auto ldA = [&](int ks, bf16x8* Ad) {
#pragma unroll
    for (int mf = 0; mf < 4; ++mf) Ad[mf] = ld8(sA, mf * 16 + lr, RB, ks * 64 + lk * 16);
  };
  auto ldB = [&](int ks, int s) {
#pragma unroll
    for (int g2 = 0; g2 < 3; ++g2)
#pragma unroll
      for (int nf = 0; nf < 2; ++nf)
        Bb[s][g2 * 2 + nf] = g8(W + (size_t)(g2 * 128 + w * 32 + nf * 16 + lr) * BK + ks * 32 + lk * 8);
  };

  ldB(0, 0); ldA(0, A0); ldB(1, 1);
#pragma unroll
  for (int ks = 0; ks < KS; ++ks) {
    bf16x8* Ac = (ks & 1) ? A1 : A0;
    bf16x8* An = (ks & 1) ? A0 : A1;
    if (ks + 1 < KS) ldA(ks + 1, An);
    if (ks + 2 < KS) ldB(ks + 2, (ks + 2) % 3);
#pragma unroll
    for (int p = 0; p < 6; ++p)
#pragma unroll
      for (int mf = 0; mf < 4; ++mf) acc[p][mf] = mm(Ac[mf], Bb[ks % 3][p], acc[p][mf]);
  }

  // ---- batched prefetch: cbase + biases (+ Uf fragments for EPI) ----
  float cb[2][4][4];
  float bia[2], boa[2], bua[2], bfa[2];
#pragma unroll
  for (int nf = 0; nf < 2; ++nf) {
    const int ch = w * 32 + nf * 16 + lr;
    bia[nf] = bp[ch]; boa[nf] = bp[ch + 128]; bua[nf] = bp[ch + 256];
    if constexpr (EPI) bfa[nf] = bf_[ch];
    if constexpr (MODE == 1 || MODE == 3) {
#pragma unroll
      for (int mf = 0; mf < 4; ++mf)
#pragma unroll
        for (int j = 0; j < 4; ++j) {
          const int nrow = 16 * mf + lk * 4 + j;
          const int src = (MODE == 1) ? sG[nrow] : sP[nrow];
          cb[nf][mf][j] = cws[(size_t)src * HS + ch];
        }
    }
  }
  bf16x8 Uff[8];
  if constexpr (EPI) {
#pragma unroll
    for (int ks = 0; ks < 4; ++ks)
#pragma unroll
      for (int nf = 0; nf < 2; ++nf)
        Uff[ks * 2 + nf] = g8(Uf + (size_t)(w * 32 + nf * 16 + lr) * HS + ks * 32 + lk * 8);
  }

  // ---- gating ----
  __bf16* hp = (MODE == 3) ? h_td : h_bu;
  float cnv[2][4][4], hnv[2][4][4];
  float psum[2] = {0.0f, 0.0f};
#pragma unroll
  for (int nf = 0; nf < 2; ++nf) {
    const int ch = w * 32 + nf * 16 + lr;
#pragma unroll
    for (int mf = 0; mf < 4; ++mf)
#pragma unroll
      for (int j = 0; j < 4; ++j) {
        const int nrow = 16 * mf + lk * 4 + j;
        float cbase = (MODE == 0) ? 0.0f : cb[nf][mf][j];
        float cn = sigf(acc[nf][mf][j] + bia[nf]) * tanh_fast(acc[4 + nf][mf][j] + bua[nf]) + cbase;
        float hn = sigf(acc[2 + nf][mf][j] + boa[nf]) * tanh_fast(cn);
        if constexpr (!LEAFOUT) hp[(size_t)sG[nrow] * HS + ch] = (__bf16)hn;
        if constexpr (EPI) { cnv[nf][mf][j] = cn; hnv[nf][mf][j] = hn; }
        if constexpr (LEAFOUT) psum[nf] += hn;
      }
  }

  if constexpr (LEAFOUT) {
#pragma unroll
    for (int nf = 0; nf < 2; ++nf) {
      float s = psum[nf];
      s += __shfl_xor(s, 16);
      s += __shfl_xor(s, 32);
      if (lk == 0) part[(size_t)blockIdx.x * 128 + w * 32 + nf * 16 + lr] = s;
    }
  }

  // ---- epilogue: f = sig(Uf h + bf); push to parents (BU) / own row (TD) ----
  if constexpr (EPI) {
    __syncthreads();
#pragma unroll
    for (int nf = 0; nf < 2; ++nf) {
      const int ch = w * 32 + nf * 16 + lr;
#pragma unroll
      for (int mf = 0; mf < 4; ++mf)
#pragma unroll
        for (int j = 0; j < 4; ++j)
          stbf(sA, 16 * mf + lk * 4 + j, RB, HB + 2 * ch, hnv[nf][mf][j]);
    }
    __syncthreads();
    f32x4 fa[4][2];
#pragma unroll
    for (int mf = 0; mf < 4; ++mf) { fa[mf][0] = 0.0f; fa[mf][1] = 0.0f; }
#pragma unroll
    for (int ks = 0; ks < 4; ++ks) {
      bf16x8 a0 = ld8(sA, lr,      RB, HB + ks * 64 + lk * 16);
      bf16x8 a1 = ld8(sA, 16 + lr, RB, HB + ks * 64 + lk * 16);
      bf16x8 a2 = ld8(sA, 32 + lr, RB, HB + ks * 64 + lk * 16);
      bf16x8 a3 = ld8(sA, 48 + lr, RB, HB + ks * 64 + lk * 16);
#pragma unroll
      for (int nf = 0; nf < 2; ++nf) {
        fa[0][nf] = mm(a0, Uff[ks * 2 + nf], fa[0][nf]);
        fa[1][nf] = mm(a1, Uff[ks * 2 + nf], fa[1][nf]);
        fa[2][nf] = mm(a2, Uff[ks * 2 + nf], fa[2][nf]);
        fa[3][nf] = mm(a3, Uff[ks * 2 + nf], fa[3][nf]);
      }
    }
#pragma unroll
    for (int nf = 0; nf < 2; ++nf) {
      const int ch = w * 32 + nf * 16 + lr;
      if constexpr (MODE == 3) {
#pragma unroll
        for (int mf = 0; mf < 4; ++mf)
#pragma unroll
          for (int j = 0; j < 4; ++j) {
            const int nrow = 16 * mf + lk * 4 + j;
            cws[(size_t)sG[nrow] * HS + ch] = sigf(fa[mf][nf][j] + bfa[nf]) * cnv[nf][mf][j];
          }
      } else {
#pragma unroll
        for (int mf = 0; mf < 4; ++mf)
#pragma unroll
          for (int p = 0; p < 2; ++p) {
            const int er = 16 * mf + lk * 4 + 2 * p;
            float f0 = sigf(fa[mf][nf][2 * p]     + bfa[nf]) * cnv[nf][mf][2 * p];
            float f1 = sigf(fa[mf][nf][2 * p + 1] + bfa[nf]) * cnv[nf][mf][2 * p + 1];
            const int gp = sP[er];
            cws[(size_t)gp * HS + ch] = f0 + f1;
            h_bu[(size_t)gp * HS + ch] = (__bf16)(hnv[nf][mf][2 * p] + hnv[nf][mf][2 * p + 1]);
          }
      }
    }
  }
}

// ---------------------------------------------------------------------------
// Merged small-levels kernel (1 block/tree): BU t=4..0 then TD t=0..4.
// Weights held in REGISTERS across all levels (BU 192 VGPR, TD 288 VGPR);
// K-loop touches only LDS + MFMA. All state LDS-resident.
// ---------------------------------------------------------------------------
__global__ void __launch_bounds__(256, 1)
small_both(const float* __restrict__ Xf,
           const __bf16* __restrict__ Wbu, const float* __restrict__ bbu,
           const __bf16* __restrict__ Ufb, const float* __restrict__ bfb,
           const __bf16* __restrict__ Wtd, const float* __restrict__ btd,
           const __bf16* __restrict__ Uft, const float* __restrict__ bft,
           __bf16* __restrict__ h_bu, __bf16* __restrict__ h_td,
           float* __restrict__ cws)
{
  __shared__ __align__(16) char sX[31 * 256];
  __shared__ __align__(16) char sH[31 * 256];
  __shared__ __align__(16) char sT[16 * 256];
  __shared__ __align__(16) char sTd[15 * 256];
  __shared__ float sCr[16][128];
  __shared__ float sFc[16][128];

  const int tid = threadIdx.x, w = tid >> 6, l = tid & 63, lr = l & 15, lk = l >> 4;
  const size_t base = (size_t)blockIdx.x * MPT * HS;

  // ---- one-time prefetch ----
  for (int idx = tid; idx < 31 * 16; idx += 256) {
    int n = idx >> 4, e = idx & 15;
    st8(sX, n, 256, e, gx8(Xf + base + (size_t)n * HS + e * 8));
  }
  { int n = tid >> 4, e = tid & 15;                       // htild t=4 (from big t=5 epi)
    st8(sT, n, 256, e, g8(h_bu + base + (size_t)(15 + n) * HS + e * 8)); }
  for (int idx = tid; idx < 16 * 32; idx += 256) {        // cred t=4
    int n = idx >> 5, e = idx & 31;
    reinterpret_cast<float4*>(&sCr[n][0])[e] =
        reinterpret_cast<const float4*>(cws + base + (size_t)(15 + n) * HS)[e];
  }
  for (int idx = tid; idx < 15 * 16; idx += 256)
    *reinterpret_cast<float4*>(sTd + idx * 16) = float4{0.f, 0.f, 0.f, 0.f};

  // =================== BU phase: t = 4..0 ===================
  {
    float bia[2], boa[2], bua[2], bfa[2];
    bf16x8 Wb[8][6], Uff[8];
#pragma unroll
    for (int nf = 0; nf < 2; ++nf) {
      const int ch = w * 32 + nf * 16 + lr;
      bia[nf] = bbu[ch]; boa[nf] = bbu[ch + 128]; bua[nf] = bbu[ch + 256]; bfa[nf] = bfb[ch];
    }
#pragma unroll
    for (int ks = 0; ks < 8; ++ks)
#pragma unroll
      for (int g2 = 0; g2 < 3; ++g2)
#pragma unroll
        for (int nf = 0; nf < 2; ++nf)
          Wb[ks][g2 * 2 + nf] =
              g8(Wbu + (size_t)(g2 * 128 + w * 32 + nf * 16 + lr) * 256 + ks * 32 + lk * 8);
#pragma unroll
    for (int ks = 0; ks < 4; ++ks)
#pragma unroll
      for (int nf = 0; nf < 2; ++nf)
        Uff[ks * 2 + nf] = g8(Ufb + (size_t)(w * 32 + nf * 16 + lr) * HS + ks * 32 + lk * 8);
    __syncthreads();

    for (int t = 4; t >= 0; --t) {
      const int cnt = 1 << t, j0 = cnt - 1;
      f32x4 acc[6];
#pragma unroll
      for (int p = 0; p < 6; ++p) acc[p] = 0.0f;
      bf16x8 Aa[3];
      auto ldA = [&](int ks, int s) {
        const int kb = (ks & 3) * 64 + lk * 16;
        Aa[s] = (ks < 4) ? ld8(sX, j0 + lr, 256, kb) : ld8(sT, lr, 256, kb);
      };
      ldA(0, 0); ldA(1, 1);
#pragma unroll
      for (int ks = 0; ks < 8; ++ks) {
        if (ks + 2 < 8) ldA(ks + 2, (ks + 2) % 3);
#pragma unroll
        for (int p = 0; p < 6; ++p) acc[p] = mm(Aa[ks % 3], Wb[ks][p], acc[p]);
      }
      float cnv[2][4], hnv[2][4];
#pragma unroll
      for (int nf = 0; nf < 2; ++nf) {
        const int ch = w * 32 + nf * 16 + lr;
#pragma unroll
        for (int j = 0; j < 4; ++j) {
          const int r = lk * 4 + j;
          float cn = sigf(acc[nf][j] + bia[nf]) * tanh_fast(acc[4 + nf][j] + bua[nf]) + sCr[r][ch];
          float hn = sigf(acc[2 + nf][j] + boa[nf]) * tanh_fast(cn);
          cnv[nf][j] = cn; hnv[nf][j] = hn;
          if (r < cnt) stbf(sH, j0 + r, 256, 2 * ch, hn);
        }
      }
      if (t == 0 && lk == 0) {
#pragma unroll
        for (int nf = 0; nf < 2; ++nf)
          h_bu[base + w * 32 + nf * 16 + lr] = (__bf16)hnv[nf][0];
      }
      __syncthreads();
      if (t > 0) {
        f32x4 fa[2]; fa[0] = 0.0f; fa[1] = 0.0f;
#pragma unroll
        for (int ks = 0; ks < 4; ++ks) {
          bf16x8 a = ld8(sH, j0 + lr, 256, ks * 64 + lk * 16);
          fa[0] = mm(a, Uff[ks * 2 + 0], fa[0]);
          fa[1] = mm(a, Uff[ks * 2 + 1], fa[1]);
        }
#pragma unroll
        for (int nf = 0; nf < 2; ++nf) {
          const int ch = w * 32 + nf * 16 + lr;
#pragma unroll
          for (int p = 0; p < 2; ++p) {
            const int pr = lk * 2 + p;
            if (pr < (cnt >> 1)) {
              float f0 = sigf(fa[nf][2 * p]     + bfa[nf]) * cnv[nf][2 * p];
              float f1 = sigf(fa[nf][2 * p + 1] + bfa[nf]) * cnv[nf][2 * p + 1];
              sCr[pr][ch] = f0 + f1;
              stbf(sT, pr, 256, 2 * ch, hnv[nf][2 * p] + hnv[nf][2 * p + 1]);
            }
          }
        }
      }
      __syncthreads();
    }
  }

  // =================== TD phase: t = 0..4 ===================
  {
    float bia[2], boa[2], bua[2], bfa[2];
    bf16x8 Wt[12][6], Uff[8];
#pragma unroll
    for (int nf = 0; nf < 2; ++nf) {
      const int ch = w * 32 + nf * 16 + lr;
      bia[nf] = btd[ch]; boa[nf] = btd[ch + 128]; bua[nf] = btd[ch + 256]; bfa[nf] = bft[ch];
    }
#pragma unroll
    for (int ks = 0; ks < 12; ++ks)
#pragma unroll
      for (int g2 = 0; g2 < 3; ++g2)
#pragma unroll
        for (int nf = 0; nf < 2; ++nf)
          Wt[ks][g2 * 2 + nf] =
              g8(Wtd + (size_t)(g2 * 128 + w * 32 + nf * 16 + lr) * 384 + ks * 32 + lk * 8);
#pragma unroll
    for (int ks = 0; ks < 4; ++ks)
#pragma unroll
      for (int nf = 0; nf < 2; ++nf)
        Uff[ks * 2 + nf] = g8(Uft + (size_t)(w * 32 + nf * 16 + lr) * HS + ks * 32 + lk * 8);

    for (int t = 0; t <= 4; ++t) {
      const int cnt = 1 << t, j0 = cnt - 1;
      f32x4 acc[6];
#pragma unroll
      for (int p = 0; p < 6; ++p) acc[p] = 0.0f;
      bf16x8 Aa[3];
      auto ldA = [&](int ks, int s) {
        const int kb = (ks & 3) * 64 + lk * 16;
        if (ks < 4)      Aa[s] = ld8(sX, j0 + lr, 256, kb);
        else if (ks < 8) Aa[s] = ld8(sH, j0 + lr, 256, kb);
        else { int pr = (j0 + lr - 1) >> 1; pr = pr < 0 ? 0 : pr;
               Aa[s] = ld8(sTd, pr, 256, kb); }
      };
      ldA(0, 0); ldA(1, 1);
#pragma unroll
      for (int ks = 0; ks < 12; ++ks) {
        if (ks + 2 < 12) ldA(ks + 2, (ks + 2) % 3);
#pragma unroll
        for (int p = 0; p < 6; ++p) acc[p] = mm(Aa[ks % 3], Wt[ks][p], acc[p]);
      }
      float cnv[2][4], hnv[2][4];
#pragma unroll
      for (int nf = 0; nf < 2; ++nf) {
        const int ch = w * 32 + nf * 16 + lr;
#pragma unroll
        for (int j = 0; j < 4; ++j) {
          const int r = lk * 4 + j;
          float cb = (t == 0) ? 0.0f : sFc[r >> 1][ch];
          float cn = sigf(acc[nf][j] + bia[nf]) * tanh_fast(acc[4 + nf][j] + bua[nf]) + cb;
          float hn = sigf(acc[2 + nf][j] + boa[nf]) * tanh_fast(cn);
          cnv[nf][j] = cn; hnv[nf][j] = hn;
          stbf(sT, r, 256, 2 * ch, hn);
          if (r < cnt && j0 + r < 15) stbf(sTd, j0 + r, 256, 2 * ch, hn);
          if (t == 4) h_td[base + (size_t)(15 + r) * HS + ch] = (__bf16)hn;
        }
      }
      __syncthreads();
      f32x4 fa[2]; fa[0] = 0.0f; fa[1] = 0.0f;
#pragma unroll
      for (int ks = 0; ks < 4; ++ks) {
        bf16x8 a = ld8(sT, lr, 256, ks * 64 + lk * 16);
        fa[0] = mm(a, Uff[ks * 2 + 0], fa[0]);
        fa[1] = mm(a, Uff[ks * 2 + 1], fa[1]);
      }
#pragma unroll
      for (int nf = 0; nf < 2; ++nf) {
        const int ch = w * 32 + nf * 16 + lr;
#pragma unroll
        for (int j = 0; j < 4; ++j) {
          const int r = lk * 4 + j;
          float fcv = sigf(fa[nf][j] + bfa[nf]) * cnv[nf][j];
          if (r < cnt) {
            if (t < 4) sFc[r][ch] = fcv;
            else       cws[base + (size_t)(15 + r) * HS + ch] = fcv;
          }
        }
      }
      __syncthreads();
    }
  }
}

// ---------------------------------------------------------------------------
__global__ void __launch_bounds__(256)
prep(const float* __restrict__ Wbu, const float* __restrict__ Ubu,
     const float* __restrict__ Wtd, const float* __restrict__ Utd,
     const float* __restrict__ Ufb, const float* __restrict__ Uft,
     __bf16* wbu, __bf16* wtd, __bf16* ufb, __bf16* uft)
{
  int i = blockIdx.x * 256 + threadIdx.x;
  if (i < 98304) {
    int r = i >> 8, c = i & 255;
    wbu[i] = (__bf16)(c < 128 ? Wbu[r * 128 + c] : Ubu[r * 128 + c - 128]);
  } else if (i < 245760) {
    int k = i - 98304; int r = k / 384, c = k - r * 384;
    wtd[k] = (__bf16)(c < 256 ? Wtd[r * 256 + c] : Utd[r * 128 + (c - 256)]);
  } else if (i < 262144) {
    int k = i - 245760; ufb[k] = (__bf16)Ufb[k];
  } else {
    int k = i - 262144; uft[k] = (__bf16)Uft[k];
  }
}

__global__ void __launch_bounds__(128)
finalize_kernel(const __bf16* __restrict__ h_bu, const float* __restrict__ part,
                float* __restrict__ out)
{
  int b = blockIdx.x, ch = threadIdx.x;
  out[(size_t)b * 256 + ch] = (float)h_bu[((size_t)b * MPT) * HS + ch];
  const float* pp = part + (size_t)b * 512 + ch;
  out[(size_t)b * 256 + 128 + ch] = (pp[0] + pp[128] + pp[256] + pp[384]) * (1.0f / 256.0f);
}

extern "C" void kernel_launch(void* const* d_in, const int* in_sizes, int n_in,
                              void* d_out, int out_size, void* d_ws, size_t ws_size,
                              hipStream_t stream) {
  const float* X     = (const float*)d_in[0];
  const float* W_bu  = (const float*)d_in[3];
  const float* U_bu  = (const float*)d_in[4];
  const float* b_bu  = (const float*)d_in[5];
  const float* Uf_bu = (const float*)d_in[6];
  const float* bf_bu = (const float*)d_in[7];
  const float* W_td  = (const float*)d_in[8];
  const float* U_td  = (const float*)d_in[9];
  const float* b_td  = (const float*)d_in[10];
  const float* Uf_td = (const float*)d_in[11];
  const float* bf_td = (const float*)d_in[12];

  char* p = (char*)d_ws;
  __bf16* wbu  = (__bf16*)p; p += (size_t)384 * 256 * 2;
  __bf16* wtd  = (__bf16*)p; p += (size_t)384 * 384 * 2;
  __bf16* ufb  = (__bf16*)p; p += (size_t)128 * 128 * 2;
  __bf16* uft  = (__bf16*)p; p += (size_t)128 * 128 * 2;
  __bf16* h_bu = (__bf16*)p; p += (size_t)NNODE * HS * 2;
  __bf16* h_td = (__bf16*)p; p += (size_t)NNODE * HS * 2;
  float*  cws  = (float*)p;  p += (size_t)NNODE * HS * 4;
  float*  part = (float*)p;  // 1024 * 128 f32

  prep<<<1088, 256, 0, stream>>>(W_bu, U_bu, W_td, U_td, Uf_bu, Uf_td, wbu, wtd, ufb, uft);

  // bottom-up big levels t=8..5
  level_big<0, true><<<1024, 256, 0, stream>>>(8, X, wbu, b_bu, ufb, bf_bu, h_bu, h_td, cws, part);
  level_big<1, true><<<512,  256, 0, stream>>>(7, X, wbu, b_bu, ufb, bf_bu, h_bu, h_td, cws, part);
  level_big<1, true><<<256,  256, 0, stream>>>(6, X, wbu, b_bu, ufb, bf_bu, h_bu, h_td, cws, part);
  level_big<1, true><<<128,  256, 0, stream>>>(5, X, wbu, b_bu, ufb, bf_bu, h_bu, h_td, cws, part);

  // merged small levels: BU t=4..0 + TD t=0..4 (weights in registers)
  small_both<<<256, 256, 0, stream>>>(X, wbu, b_bu, ufb, bf_bu,
                                      wtd, b_td, uft, bf_td, h_bu, h_td, cws);

  // top-down big levels t=5..8
  level_big<3, true ><<<128,  256, 0, stream>>>(5, X, wtd, b_td, uft, bf_td, h_bu, h_td, cws, part);
  level_big<3, true ><<<256,  256, 0, stream>>>(6, X, wtd, b_td, uft, bf_td, h_bu, h_td, cws, part);
  level_big<3, true ><<<512,  256, 0, stream>>>(7, X, wtd, b_td, uft, bf_td, h_bu, h_td, cws, part);
  level_big<3, false><<<1024, 256, 0, stream>>>(8, X, wtd, b_td, uft, bf_td, h_bu, h_td, cws, part);

  finalize_kernel<<<256, 128, 0, stream>>>(h_bu, part, (float*)d_out);
}